// Round 5
// baseline (562.873 us; speedup 1.0000x reference)
//
#include <hip/hip_runtime.h>
#include <cstdint>
#include <cstddef>

// Problem constants
#define Bn 16
#define Tn 128
#define Dn 8192    // C*H*W
#define Fn 16      // NUM_FEAT
#define Gn 4096    // NUM_FEAT*H*W
#define MT (Bn*Tn) // 2048 rows

#define QKP 4      // qk split-K parts

typedef __attribute__((ext_vector_type(8))) short short8;
typedef __attribute__((ext_vector_type(4))) float f32x4;

__device__ inline short f2bf(float f) {
    union { float f; uint32_t u; } c; c.f = f;
    uint32_t u = c.u;
    uint32_t r = (u + 0x7FFFu + ((u >> 16) & 1u)) >> 16;
    return (short)(r & 0xFFFFu);
}

__device__ inline short8 cvt8(float4 a, float4 b) {
    short8 v;
    v[0] = f2bf(a.x); v[1] = f2bf(a.y); v[2] = f2bf(a.z); v[3] = f2bf(a.w);
    v[4] = f2bf(b.x); v[5] = f2bf(b.y); v[6] = f2bf(b.z); v[7] = f2bf(b.w);
    return v;
}

// ---------------------------------------------------------------------------
// Fused fp32->bf16 convert for x1 and w3 (one launch, grid-stride).
// ---------------------------------------------------------------------------
#define N8_X1 (MT * Dn / 8)   // 2,097,152
#define N8_W3 ((size_t)Gn * Dn / 8)   // 4,194,304

__global__ __launch_bounds__(256) void cvt2_kernel(
    const float* __restrict__ x1, const float* __restrict__ w3,
    short* __restrict__ x1b, short* __restrict__ w3b)
{
    const size_t total = N8_X1 + N8_W3;
    size_t i = (size_t)blockIdx.x * 256 + threadIdx.x;
    const size_t stride = (size_t)gridDim.x * 256;
    for (; i < total; i += stride) {
        if (i < N8_X1) {
            const float4* s = ((const float4*)x1) + i * 2;
            ((short8*)x1b)[i] = cvt8(s[0], s[1]);
        } else {
            const size_t j = i - N8_X1;
            const float4* s = ((const float4*)w3) + j * 2;
            ((short8*)w3b)[j] = cvt8(s[0], s[1]);
        }
    }
}

// ---------------------------------------------------------------------------
// qk skinny GEMM, split-K x4: partial q/k (NO bias) per K-quarter.
// Grid (256, QKP) x 256 threads: blockIdx.x = (16-row m-tile, q-or-k),
// blockIdx.y = K-quarter. Wave w covers K-span [kq*2048 + w*512, +512).
// Partials qp/kp layout [QKP][MT][Fn] fp32; summed (with bias) in attn_kernel.
// 1024 blocks -> 4 blocks/CU (was 1/CU): fixes latency-bound staging.
// ---------------------------------------------------------------------------
__global__ __launch_bounds__(256) void qk_gemm_kernel(
    const short* __restrict__ x1b, const float* __restrict__ x2,
    const float* __restrict__ w1, const float* __restrict__ w2,
    float* __restrict__ qp, float* __restrict__ kp)
{
    __shared__ float red[4][16][16];
    const int tid = threadIdx.x;
    const int tile = blockIdx.x >> 1;
    const int isK  = blockIdx.x & 1;
    const int kq   = blockIdx.y;
    const int m0 = tile * 16;
    const int wave = tid >> 6, lane = tid & 63;
    const int quad = lane >> 4, r = lane & 15;
    const int kbase = kq * (Dn / QKP) + wave * (Dn / QKP / 4);   // kq*2048 + w*512

    f32x4 acc = {};

    if (!isK) {
        const short* ap = x1b + (size_t)(m0 + r) * Dn + kbase + quad * 8;
        const float* bp = w1 + (size_t)r * Dn + kbase + quad * 8;
        #pragma unroll 4
        for (int it = 0; it < 16; ++it) {
            short8 af = *(const short8*)(ap + it * 32);
            const float4* b4 = (const float4*)(bp + it * 32);
            short8 bf = cvt8(b4[0], b4[1]);
            acc = __builtin_amdgcn_mfma_f32_16x16x32_bf16(af, bf, acc, 0, 0, 0);
        }
    } else {
        const float* apf = x2 + (size_t)(m0 + r) * Dn + kbase + quad * 8;
        const float* bp  = w2 + (size_t)r * Dn + kbase + quad * 8;
        #pragma unroll 4
        for (int it = 0; it < 16; ++it) {
            const float4* a4 = (const float4*)(apf + it * 32);
            short8 af = cvt8(a4[0], a4[1]);
            const float4* b4 = (const float4*)(bp + it * 32);
            short8 bf = cvt8(b4[0], b4[1]);
            acc = __builtin_amdgcn_mfma_f32_16x16x32_bf16(af, bf, acc, 0, 0, 0);
        }
    }

    // C/D: col(n=f)=lane&15, row(m)=quad*4+reg
    #pragma unroll
    for (int reg = 0; reg < 4; ++reg)
        red[wave][quad * 4 + reg][r] = acc[reg];
    __syncthreads();

    const int m = tid >> 4, f = tid & 15;
    float s = red[0][m][f] + red[1][m][f] + red[2][m][f] + red[3][m][f];
    float* dst = isK ? kp : qp;
    dst[((size_t)kq * MT + m0 + m) * Fn + f] = s;
}

// ---------------------------------------------------------------------------
// attn: sums qk partials (+bias), scores = q @ k^T per batch; softmax over t
// (axis=1 = per column s). Wave-per-column: grid (Bn, Tn/4) x 256; wave w owns
// s = blockIdx.y*4 + w; lane owns t=lane, t=lane+64. Butterfly shfl reduce.
// ---------------------------------------------------------------------------
__global__ __launch_bounds__(256) void attn_kernel(
    const float* __restrict__ qp, const float* __restrict__ kp,
    const float* __restrict__ b1, const float* __restrict__ b2,
    short* __restrict__ attn16)
{
    __shared__ float qs[Tn * 17];
    const int b = blockIdx.x;
    const int tid = threadIdx.x;
    const int wave = tid >> 6, lane = tid & 63;
    const int s = blockIdx.y * 4 + wave;

    for (int i = tid; i < Tn * Fn; i += 256) {
        float v = b1[i & 15];
        #pragma unroll
        for (int p = 0; p < QKP; ++p)
            v += qp[(size_t)p * MT * Fn + b * Tn * Fn + i];
        qs[(i >> 4) * 17 + (i & 15)] = v;
    }
    __syncthreads();

    float kr[16];
    #pragma unroll
    for (int f = 0; f < 16; ++f) {
        float v = b2[f];
        #pragma unroll
        for (int p = 0; p < QKP; ++p)
            v += kp[((size_t)p * MT + b * Tn + s) * Fn + f];
        kr[f] = v;
    }

    const int t0 = lane, t1 = lane + 64;
    float sc0 = 0.f, sc1 = 0.f;
    #pragma unroll
    for (int f = 0; f < 16; ++f) {
        sc0 += qs[t0 * 17 + f] * kr[f];
        sc1 += qs[t1 * 17 + f] * kr[f];
    }
    float m = fmaxf(sc0, sc1);
    #pragma unroll
    for (int off = 32; off > 0; off >>= 1)
        m = fmaxf(m, __shfl_xor(m, off, 64));
    const float e0 = __expf(sc0 - m), e1 = __expf(sc1 - m);
    float ssum = e0 + e1;
    #pragma unroll
    for (int off = 32; off > 0; off >>= 1)
        ssum += __shfl_xor(ssum, off, 64);
    const float inv = 1.f / ssum;

    short* ap = attn16 + (size_t)b * Tn * Tn;
    ap[t0 * Tn + s] = f2bf(e0 * inv);
    ap[t1 * Tn + s] = f2bf(e1 * inv);
}

// ---------------------------------------------------------------------------
// Big GEMM, split-K (runtime), BK=64: half the barrier/vmcnt drains of BK=32
// (the 2-phase critical path is stage+drain+barrier, not LDS reads — m233).
// DETERMINISTIC partials: slice z writes its own fp32 buffer. KSPLIT=2 (4 was
// measured worse: reg-capped at 4 blocks/CU, extra split only adds traffic).
// LDS 2x16KB = 32 KB -> still 4 blocks/CU.
// ---------------------------------------------------------------------------
#define BK 32     // fallback gemm + out_gemm K-step
#define BKG 64    // split gemm K-step

__global__ __launch_bounds__(256) void gemm_v_split_kernel(
    const short* __restrict__ A, const short* __restrict__ Bw,
    float* __restrict__ vTf, const int kspan)
{
    __shared__ __attribute__((aligned(16))) short As[128 * BKG];  // 16 KB
    __shared__ __attribute__((aligned(16))) short Bs[128 * BKG];  // 16 KB

    const int tid = threadIdx.x;
    const int m0 = blockIdx.y * 128;        // g dim (4096)
    const int n0 = blockIdx.x * 128;        // bt dim (2048)
    const int z  = blockIdx.z;              // K slice
    const int kbase = z * kspan;
    float* outp = vTf + (size_t)z * Gn * MT;
    const int wave = tid >> 6, lane = tid & 63;
    const int wm = (wave >> 1) * 64, wn = (wave & 1) * 64;
    const int quad = lane >> 4, r = lane & 15;

    // Staging: 8 threads/row (8x8 shorts = 128B), 256 threads = 32 rows/instr.
    const int srow = tid >> 3;          // 0..31
    const int scol = (tid & 7) * 8;     // 0..56
    const short* gA = A  + (size_t)(m0 + srow) * Dn + kbase + scol;
    const short* gB = Bw + (size_t)(n0 + srow) * Dn + kbase + scol;
    short* lA = &As[srow * BKG + scol];
    short* lB = &Bs[srow * BKG + scol];

    f32x4 acc[4][4] = {};

    #pragma unroll 1
    for (int k0 = 0; k0 < kspan; k0 += BKG) {
        __syncthreads();
        #pragma unroll
        for (int t = 0; t < 4; ++t) {
            __builtin_amdgcn_global_load_lds(
                (const __attribute__((address_space(1))) void*)(gA + k0 + (size_t)(t * 32) * Dn),
                (__attribute__((address_space(3))) void*)(lA + t * 32 * BKG), 16, 0, 0);
            __builtin_amdgcn_global_load_lds(
                (const __attribute__((address_space(1))) void*)(gB + k0 + (size_t)(t * 32) * Dn),
                (__attribute__((address_space(3))) void*)(lB + t * 32 * BKG), 16, 0, 0);
        }
        __syncthreads();

        #pragma unroll
        for (int half = 0; half < 2; ++half) {
            short8 af[4], bf[4];
            #pragma unroll
            for (int i = 0; i < 4; ++i)
                af[i] = *(const short8*)&As[(wm + i * 16 + r) * BKG + half * 32 + quad * 8];
            #pragma unroll
            for (int j = 0; j < 4; ++j)
                bf[j] = *(const short8*)&Bs[(wn + j * 16 + r) * BKG + half * 32 + quad * 8];

            #pragma unroll
            for (int i = 0; i < 4; ++i)
                #pragma unroll
                for (int j = 0; j < 4; ++j)
                    acc[i][j] = __builtin_amdgcn_mfma_f32_16x16x32_bf16(
                        af[i], bf[j], acc[i][j], 0, 0, 0);
        }
    }

    // C/D: col(n=bt)=lane&15 group, row(m=g)=quad*4+reg. Plain fp32 stores.
    #pragma unroll
    for (int i = 0; i < 4; ++i) {
        #pragma unroll
        for (int reg = 0; reg < 4; ++reg) {
            const int rowg = m0 + wm + i * 16 + quad * 4 + reg;
            #pragma unroll
            for (int j = 0; j < 4; ++j) {
                const int col = n0 + wn + j * 16 + r;
                outp[(size_t)rowg * MT + col] = acc[i][j][reg];
            }
        }
    }
}

// Sum the nparts K-slice partials + bias, fp32->bf16. row g = i>>8.
__global__ __launch_bounds__(256) void vt_cvt_kernel(
    const float* __restrict__ vTf, const float* __restrict__ bias,
    short* __restrict__ vT, const int nparts)
{
    const size_t N8 = (size_t)Gn * MT / 8;   // 1,048,576
    size_t i = (size_t)blockIdx.x * 256 + threadIdx.x;
    const size_t stride = (size_t)gridDim.x * 256;
    for (; i < N8; i += stride) {
        const float bv = bias[i >> 8];
        float4 a = {bv, bv, bv, bv}, b = {bv, bv, bv, bv};
        for (int p = 0; p < nparts; ++p) {
            const float4* pp = (const float4*)(vTf + (size_t)p * Gn * MT);
            float4 a1 = pp[i * 2], b1 = pp[i * 2 + 1];
            a.x += a1.x; a.y += a1.y; a.z += a1.z; a.w += a1.w;
            b.x += b1.x; b.y += b1.y; b.z += b1.z; b.w += b1.w;
        }
        ((short8*)vT)[i] = cvt8(a, b);
    }
}

// ---------------------------------------------------------------------------
// Fallback (ws too small for split-K): original single-pass big GEMM (BK=32).
// ---------------------------------------------------------------------------
__global__ __launch_bounds__(256) void gemm_v_kernel(
    const short* __restrict__ A, const short* __restrict__ Bw,
    const float* __restrict__ bias, short* __restrict__ vT)
{
    __shared__ __attribute__((aligned(16))) short As[128 * BK];
    __shared__ __attribute__((aligned(16))) short Bs[128 * BK];

    const int tid = threadIdx.x;
    const int m0 = blockIdx.y * 128;   // g dim (4096)
    const int n0 = blockIdx.x * 128;   // bt dim (2048)
    const int wave = tid >> 6, lane = tid & 63;
    const int wm = (wave >> 1) * 64, wn = (wave & 1) * 64;
    const int quad = lane >> 4, r = lane & 15;

    const int srow = wave * 32 + (lane >> 2);
    const int scol = (lane & 3) * 8;
    const short* gA = A  + (size_t)(m0 + srow) * Dn + scol;
    const short* gB = Bw + (size_t)(n0 + srow) * Dn + scol;
    short* lA = &As[srow * BK + scol];
    short* lB = &Bs[srow * BK + scol];

    f32x4 acc[4][4] = {};

    #pragma unroll 1
    for (int k0 = 0; k0 < Dn; k0 += BK) {
        __syncthreads();
        __builtin_amdgcn_global_load_lds(
            (const __attribute__((address_space(1))) void*)(gA + k0),
            (__attribute__((address_space(3))) void*)lA, 16, 0, 0);
        __builtin_amdgcn_global_load_lds(
            (const __attribute__((address_space(1))) void*)(gA + k0 + (size_t)16 * Dn),
            (__attribute__((address_space(3))) void*)(lA + 16 * BK), 16, 0, 0);
        __builtin_amdgcn_global_load_lds(
            (const __attribute__((address_space(1))) void*)(gB + k0),
            (__attribute__((address_space(3))) void*)lB, 16, 0, 0);
        __builtin_amdgcn_global_load_lds(
            (const __attribute__((address_space(1))) void*)(gB + k0 + (size_t)16 * Dn),
            (__attribute__((address_space(3))) void*)(lB + 16 * BK), 16, 0, 0);
        __syncthreads();

        short8 af[4], bf[4];
        #pragma unroll
        for (int i = 0; i < 4; ++i)
            af[i] = *(const short8*)&As[(wm + i * 16 + r) * BK + quad * 8];
        #pragma unroll
        for (int j = 0; j < 4; ++j)
            bf[j] = *(const short8*)&Bs[(wn + j * 16 + r) * BK + quad * 8];

        #pragma unroll
        for (int i = 0; i < 4; ++i)
            #pragma unroll
            for (int j = 0; j < 4; ++j)
                acc[i][j] = __builtin_amdgcn_mfma_f32_16x16x32_bf16(
                    af[i], bf[j], acc[i][j], 0, 0, 0);
    }

    #pragma unroll
    for (int i = 0; i < 4; ++i) {
        #pragma unroll
        for (int reg = 0; reg < 4; ++reg) {
            const int rowg = m0 + wm + i * 16 + quad * 4 + reg;
            const float bv = bias[rowg];
            #pragma unroll
            for (int j = 0; j < 4; ++j) {
                const int col = n0 + wn + j * 16 + r;
                vT[(size_t)rowg * MT + col] = f2bf(acc[i][j][reg] + bv);
            }
        }
    }
}

// ---------------------------------------------------------------------------
// out GEMM per batch: out[t][g] = sum_s attn[t][s] * vT[g][s].
// 128(t) x 64(g) tile per block -> grid (Gn/64, Bn) = 1024 blocks (4/CU).
// ---------------------------------------------------------------------------
__global__ __launch_bounds__(256) void out_gemm_kernel(
    const short* __restrict__ attn16, const short* __restrict__ vT,
    float* __restrict__ out)
{
    __shared__ __attribute__((aligned(16))) short As[128 * BK];  // 8 KB
    __shared__ __attribute__((aligned(16))) short Bs[64 * BK];   // 4 KB

    const int tid = threadIdx.x;
    const int b  = blockIdx.y;
    const int n0 = blockIdx.x * 64;    // g dim
    const int wave = tid >> 6, lane = tid & 63;
    const int wm = (wave >> 1) * 64, wn = (wave & 1) * 32;
    const int quad = lane >> 4, r = lane & 15;

    const int srowA = wave * 32 + (lane >> 2);   // 0..127 over 2 instrs
    const int srowB = wave * 16 + (lane >> 2);   // 0..63, 1 instr
    const int scol = (lane & 3) * 8;
    const short* gA = attn16 + (size_t)b * Tn * Tn + srowA * Tn + scol;   // t rows
    const short* gB = vT + (size_t)(n0 + srowB) * MT + b * Tn + scol;     // g rows
    short* lA = &As[srowA * BK + scol];
    short* lB = &Bs[srowB * BK + scol];

    f32x4 acc[4][2] = {};

    #pragma unroll 1
    for (int k0 = 0; k0 < Tn; k0 += BK) {
        __syncthreads();
        __builtin_amdgcn_global_load_lds(
            (const __attribute__((address_space(1))) void*)(gA + k0),
            (__attribute__((address_space(3))) void*)lA, 16, 0, 0);
        __builtin_amdgcn_global_load_lds(
            (const __attribute__((address_space(1))) void*)(gA + k0 + 16 * Tn),
            (__attribute__((address_space(3))) void*)(lA + 16 * BK), 16, 0, 0);
        __builtin_amdgcn_global_load_lds(
            (const __attribute__((address_space(1))) void*)(gB + k0),
            (__attribute__((address_space(3))) void*)lB, 16, 0, 0);
        __syncthreads();

        short8 af[4], bf[2];
        #pragma unroll
        for (int i = 0; i < 4; ++i)
            af[i] = *(const short8*)&As[(wm + i * 16 + r) * BK + quad * 8];
        #pragma unroll
        for (int j = 0; j < 2; ++j)
            bf[j] = *(const short8*)&Bs[(wn + j * 16 + r) * BK + quad * 8];

        #pragma unroll
        for (int i = 0; i < 4; ++i)
            #pragma unroll
            for (int j = 0; j < 2; ++j)
                acc[i][j] = __builtin_amdgcn_mfma_f32_16x16x32_bf16(
                    af[i], bf[j], acc[i][j], 0, 0, 0);
    }

    // C/D: row(m=t)=quad*4+reg, col(n=g)=r group. fp32 out [b][t][g].
    #pragma unroll
    for (int j = 0; j < 2; ++j) {
        const int col = n0 + wn + j * 16 + r;
        #pragma unroll
        for (int i = 0; i < 4; ++i) {
            #pragma unroll
            for (int reg = 0; reg < 4; ++reg) {
                const int rowt = wm + i * 16 + quad * 4 + reg;
                out[((size_t)(b * Tn + rowt)) * Gn + col] = acc[i][j][reg];
            }
        }
    }
}

// ---------------------------------------------------------------------------
extern "C" void kernel_launch(void* const* d_in, const int* in_sizes, int n_in,
                              void* d_out, int out_size, void* d_ws, size_t ws_size,
                              hipStream_t stream)
{
    const float* x1 = (const float*)d_in[0];
    const float* x2 = (const float*)d_in[1];
    const float* w1 = (const float*)d_in[2];
    const float* b1 = (const float*)d_in[3];
    const float* w2 = (const float*)d_in[4];
    const float* b2 = (const float*)d_in[5];
    const float* w3 = (const float*)d_in[6];
    const float* b3 = (const float*)d_in[7];
    float* out = (float*)d_out;

    // Workspace: qp,kp fp32 partials; attn16, vT, x1b, w3b bf16; vTf fp32 xK.
    float* qp     = (float*)d_ws;
    float* kp     = qp + (size_t)QKP * MT * Fn;
    short* attn16 = (short*)(kp + (size_t)QKP * MT * Fn);
    short* vT     = attn16 + (size_t)Bn * Tn * Tn;
    short* x1b    = vT + (size_t)Gn * MT;
    short* w3b    = x1b + (size_t)MT * Dn;
    float* vTf    = (float*)(w3b + (size_t)Gn * Dn);

    const size_t base_need =
        (size_t)QKP * MT * Fn * 4 * 2 +         // qp,kp
        (size_t)Bn * Tn * Tn * 2 +              // attn16
        (size_t)Gn * MT * 2 +                   // vT
        (size_t)MT * Dn * 2 +                   // x1b
        (size_t)Gn * Dn * 2;                    // w3b
    const size_t psize = (size_t)Gn * MT * 4;   // 32 MB per partial

    const int ksplit = (ws_size >= base_need + 2 * psize) ? 2 : 0;

    cvt2_kernel<<<4096, 256, 0, stream>>>(x1, w3, x1b, w3b);
    qk_gemm_kernel<<<dim3(256, QKP), 256, 0, stream>>>(x1b, x2, w1, w2, qp, kp);
    attn_kernel<<<dim3(Bn, Tn / 4), 256, 0, stream>>>(qp, kp, b1, b2, attn16);

    if (ksplit) {
        gemm_v_split_kernel<<<dim3(MT / 128, Gn / 128, ksplit), 256, 0, stream>>>(
            w3b, x1b, vTf, Dn / ksplit);
        vt_cvt_kernel<<<2048, 256, 0, stream>>>(vTf, b3, vT, ksplit);
    } else {
        gemm_v_kernel<<<dim3(MT / 128, Gn / 128), 256, 0, stream>>>(w3b, x1b, b3, vT);
    }

    out_gemm_kernel<<<dim3(Gn / 64, Bn), 256, 0, stream>>>(attn16, vT, out);
}

// Round 6
// 547.415 us; speedup vs baseline: 1.0282x; 1.0282x over previous
//
#include <hip/hip_runtime.h>
#include <cstdint>
#include <cstddef>

// Problem constants
#define Bn 16
#define Tn 128
#define Dn 8192    // C*H*W
#define Fn 16      // NUM_FEAT
#define Gn 4096    // NUM_FEAT*H*W
#define MT (Bn*Tn) // 2048 rows

#define QKP 4      // qk split-K parts

typedef __attribute__((ext_vector_type(8))) short short8;
typedef __attribute__((ext_vector_type(4))) float f32x4;

__device__ inline short f2bf(float f) {
    union { float f; uint32_t u; } c; c.f = f;
    uint32_t u = c.u;
    uint32_t r = (u + 0x7FFFu + ((u >> 16) & 1u)) >> 16;
    return (short)(r & 0xFFFFu);
}

__device__ inline short8 cvt8(float4 a, float4 b) {
    short8 v;
    v[0] = f2bf(a.x); v[1] = f2bf(a.y); v[2] = f2bf(a.z); v[3] = f2bf(a.w);
    v[4] = f2bf(b.x); v[5] = f2bf(b.y); v[6] = f2bf(b.z); v[7] = f2bf(b.w);
    return v;
}

// ---------------------------------------------------------------------------
// Fused fp32->bf16 convert for x1 and w3 (one launch, grid-stride).
// ---------------------------------------------------------------------------
#define N8_X1 (MT * Dn / 8)   // 2,097,152
#define N8_W3 ((size_t)Gn * Dn / 8)   // 4,194,304

__global__ __launch_bounds__(256) void cvt2_kernel(
    const float* __restrict__ x1, const float* __restrict__ w3,
    short* __restrict__ x1b, short* __restrict__ w3b)
{
    const size_t total = N8_X1 + N8_W3;
    size_t i = (size_t)blockIdx.x * 256 + threadIdx.x;
    const size_t stride = (size_t)gridDim.x * 256;
    for (; i < total; i += stride) {
        if (i < N8_X1) {
            const float4* s = ((const float4*)x1) + i * 2;
            ((short8*)x1b)[i] = cvt8(s[0], s[1]);
        } else {
            const size_t j = i - N8_X1;
            const float4* s = ((const float4*)w3) + j * 2;
            ((short8*)w3b)[j] = cvt8(s[0], s[1]);
        }
    }
}

// ---------------------------------------------------------------------------
// qk skinny GEMM, split-K x4: partial q/k (NO bias) per K-quarter.
// Grid (256, QKP) x 256 threads. Partials summed (with bias) in attn_kernel.
// ---------------------------------------------------------------------------
__global__ __launch_bounds__(256) void qk_gemm_kernel(
    const short* __restrict__ x1b, const float* __restrict__ x2,
    const float* __restrict__ w1, const float* __restrict__ w2,
    float* __restrict__ qp, float* __restrict__ kp)
{
    __shared__ float red[4][16][16];
    const int tid = threadIdx.x;
    const int tile = blockIdx.x >> 1;
    const int isK  = blockIdx.x & 1;
    const int kq   = blockIdx.y;
    const int m0 = tile * 16;
    const int wave = tid >> 6, lane = tid & 63;
    const int quad = lane >> 4, r = lane & 15;
    const int kbase = kq * (Dn / QKP) + wave * (Dn / QKP / 4);   // kq*2048 + w*512

    f32x4 acc = {};

    if (!isK) {
        const short* ap = x1b + (size_t)(m0 + r) * Dn + kbase + quad * 8;
        const float* bp = w1 + (size_t)r * Dn + kbase + quad * 8;
        #pragma unroll 4
        for (int it = 0; it < 16; ++it) {
            short8 af = *(const short8*)(ap + it * 32);
            const float4* b4 = (const float4*)(bp + it * 32);
            short8 bf = cvt8(b4[0], b4[1]);
            acc = __builtin_amdgcn_mfma_f32_16x16x32_bf16(af, bf, acc, 0, 0, 0);
        }
    } else {
        const float* apf = x2 + (size_t)(m0 + r) * Dn + kbase + quad * 8;
        const float* bp  = w2 + (size_t)r * Dn + kbase + quad * 8;
        #pragma unroll 4
        for (int it = 0; it < 16; ++it) {
            const float4* a4 = (const float4*)(apf + it * 32);
            short8 af = cvt8(a4[0], a4[1]);
            const float4* b4 = (const float4*)(bp + it * 32);
            short8 bf = cvt8(b4[0], b4[1]);
            acc = __builtin_amdgcn_mfma_f32_16x16x32_bf16(af, bf, acc, 0, 0, 0);
        }
    }

    // C/D: col(n=f)=lane&15, row(m)=quad*4+reg
    #pragma unroll
    for (int reg = 0; reg < 4; ++reg)
        red[wave][quad * 4 + reg][r] = acc[reg];
    __syncthreads();

    const int m = tid >> 4, f = tid & 15;
    float s = red[0][m][f] + red[1][m][f] + red[2][m][f] + red[3][m][f];
    float* dst = isK ? kp : qp;
    dst[((size_t)kq * MT + m0 + m) * Fn + f] = s;
}

// ---------------------------------------------------------------------------
// attn: sums qk partials (+bias), scores = q @ k^T per batch; softmax over t
// (axis=1 = per column s). Wave-per-column: grid (Bn, Tn/4) x 256; wave w owns
// s = blockIdx.y*4 + w; lane owns t=lane, t=lane+64. Butterfly shfl reduce.
// ---------------------------------------------------------------------------
__global__ __launch_bounds__(256) void attn_kernel(
    const float* __restrict__ qp, const float* __restrict__ kp,
    const float* __restrict__ b1, const float* __restrict__ b2,
    short* __restrict__ attn16)
{
    __shared__ float qs[Tn * 17];
    const int b = blockIdx.x;
    const int tid = threadIdx.x;
    const int wave = tid >> 6, lane = tid & 63;
    const int s = blockIdx.y * 4 + wave;

    for (int i = tid; i < Tn * Fn; i += 256) {
        float v = b1[i & 15];
        #pragma unroll
        for (int p = 0; p < QKP; ++p)
            v += qp[(size_t)p * MT * Fn + b * Tn * Fn + i];
        qs[(i >> 4) * 17 + (i & 15)] = v;
    }
    __syncthreads();

    float kr[16];
    #pragma unroll
    for (int f = 0; f < 16; ++f) {
        float v = b2[f];
        #pragma unroll
        for (int p = 0; p < QKP; ++p)
            v += kp[((size_t)p * MT + b * Tn + s) * Fn + f];
        kr[f] = v;
    }

    const int t0 = lane, t1 = lane + 64;
    float sc0 = 0.f, sc1 = 0.f;
    #pragma unroll
    for (int f = 0; f < 16; ++f) {
        sc0 += qs[t0 * 17 + f] * kr[f];
        sc1 += qs[t1 * 17 + f] * kr[f];
    }
    float m = fmaxf(sc0, sc1);
    #pragma unroll
    for (int off = 32; off > 0; off >>= 1)
        m = fmaxf(m, __shfl_xor(m, off, 64));
    const float e0 = __expf(sc0 - m), e1 = __expf(sc1 - m);
    float ssum = e0 + e1;
    #pragma unroll
    for (int off = 32; off > 0; off >>= 1)
        ssum += __shfl_xor(ssum, off, 64);
    const float inv = 1.f / ssum;

    short* ap = attn16 + (size_t)b * Tn * Tn;
    ap[t0 * Tn + s] = f2bf(e0 * inv);
    ap[t1 * Tn + s] = f2bf(e1 * inv);
}

// ---------------------------------------------------------------------------
// Big GEMM, split-K (KSPLIT=2), BK=32 — the measured-best config (R3: 201 us,
// MfmaUtil 30.7, Occ 37.4). R5's BK=64 regressed (VGPR 92 -> occ 20%, 128B row
// stride -> 16-way LDS conflict 5e7): REVERTED. DETERMINISTIC partials: slice z
// writes its own fp32 buffer (no atomics, no memset, no host API).
// ---------------------------------------------------------------------------
#define BK 32

__global__ __launch_bounds__(256) void gemm_v_split_kernel(
    const short* __restrict__ A, const short* __restrict__ Bw,
    float* __restrict__ vTf, const int kspan)
{
    __shared__ __attribute__((aligned(16))) short As[128 * BK];
    __shared__ __attribute__((aligned(16))) short Bs[128 * BK];

    const int tid = threadIdx.x;
    const int m0 = blockIdx.y * 128;        // g dim (4096)
    const int n0 = blockIdx.x * 128;        // bt dim (2048)
    const int z  = blockIdx.z;              // K slice
    const int kbase = z * kspan;
    float* outp = vTf + (size_t)z * Gn * MT;
    const int wave = tid >> 6, lane = tid & 63;
    const int wm = (wave >> 1) * 64, wn = (wave & 1) * 64;
    const int quad = lane >> 4, r = lane & 15;

    const int srow = wave * 32 + (lane >> 2);
    const int scol = (lane & 3) * 8;
    const short* gA = A  + (size_t)(m0 + srow) * Dn + kbase + scol;
    const short* gB = Bw + (size_t)(n0 + srow) * Dn + kbase + scol;
    short* lA = &As[srow * BK + scol];
    short* lB = &Bs[srow * BK + scol];

    f32x4 acc[4][4] = {};

    #pragma unroll 1
    for (int k0 = 0; k0 < kspan; k0 += BK) {
        __syncthreads();
        __builtin_amdgcn_global_load_lds(
            (const __attribute__((address_space(1))) void*)(gA + k0),
            (__attribute__((address_space(3))) void*)lA, 16, 0, 0);
        __builtin_amdgcn_global_load_lds(
            (const __attribute__((address_space(1))) void*)(gA + k0 + (size_t)16 * Dn),
            (__attribute__((address_space(3))) void*)(lA + 16 * BK), 16, 0, 0);
        __builtin_amdgcn_global_load_lds(
            (const __attribute__((address_space(1))) void*)(gB + k0),
            (__attribute__((address_space(3))) void*)lB, 16, 0, 0);
        __builtin_amdgcn_global_load_lds(
            (const __attribute__((address_space(1))) void*)(gB + k0 + (size_t)16 * Dn),
            (__attribute__((address_space(3))) void*)(lB + 16 * BK), 16, 0, 0);
        __syncthreads();

        short8 af[4], bf[4];
        #pragma unroll
        for (int i = 0; i < 4; ++i)
            af[i] = *(const short8*)&As[(wm + i * 16 + r) * BK + quad * 8];
        #pragma unroll
        for (int j = 0; j < 4; ++j)
            bf[j] = *(const short8*)&Bs[(wn + j * 16 + r) * BK + quad * 8];

        #pragma unroll
        for (int i = 0; i < 4; ++i)
            #pragma unroll
            for (int j = 0; j < 4; ++j)
                acc[i][j] = __builtin_amdgcn_mfma_f32_16x16x32_bf16(
                    af[i], bf[j], acc[i][j], 0, 0, 0);
    }

    // C/D: col(n=bt)=lane&15 group, row(m=g)=quad*4+reg. Plain fp32 stores.
    #pragma unroll
    for (int i = 0; i < 4; ++i) {
        #pragma unroll
        for (int reg = 0; reg < 4; ++reg) {
            const int rowg = m0 + wm + i * 16 + quad * 4 + reg;
            #pragma unroll
            for (int j = 0; j < 4; ++j) {
                const int col = n0 + wn + j * 16 + r;
                outp[(size_t)rowg * MT + col] = acc[i][j][reg];
            }
        }
    }
}

// Sum the nparts K-slice partials + bias, fp32->bf16. row g = i>>8.
__global__ __launch_bounds__(256) void vt_cvt_kernel(
    const float* __restrict__ vTf, const float* __restrict__ bias,
    short* __restrict__ vT, const int nparts)
{
    const size_t N8 = (size_t)Gn * MT / 8;   // 1,048,576
    size_t i = (size_t)blockIdx.x * 256 + threadIdx.x;
    const size_t stride = (size_t)gridDim.x * 256;
    for (; i < N8; i += stride) {
        const float bv = bias[i >> 8];
        float4 a = {bv, bv, bv, bv}, b = {bv, bv, bv, bv};
        for (int p = 0; p < nparts; ++p) {
            const float4* pp = (const float4*)(vTf + (size_t)p * Gn * MT);
            float4 a1 = pp[i * 2], b1 = pp[i * 2 + 1];
            a.x += a1.x; a.y += a1.y; a.z += a1.z; a.w += a1.w;
            b.x += b1.x; b.y += b1.y; b.z += b1.z; b.w += b1.w;
        }
        ((short8*)vT)[i] = cvt8(a, b);
    }
}

// ---------------------------------------------------------------------------
// Fallback (ws too small for split-K): original single-pass big GEMM (BK=32).
// ---------------------------------------------------------------------------
__global__ __launch_bounds__(256) void gemm_v_kernel(
    const short* __restrict__ A, const short* __restrict__ Bw,
    const float* __restrict__ bias, short* __restrict__ vT)
{
    __shared__ __attribute__((aligned(16))) short As[128 * BK];
    __shared__ __attribute__((aligned(16))) short Bs[128 * BK];

    const int tid = threadIdx.x;
    const int m0 = blockIdx.y * 128;   // g dim (4096)
    const int n0 = blockIdx.x * 128;   // bt dim (2048)
    const int wave = tid >> 6, lane = tid & 63;
    const int wm = (wave >> 1) * 64, wn = (wave & 1) * 64;
    const int quad = lane >> 4, r = lane & 15;

    const int srow = wave * 32 + (lane >> 2);
    const int scol = (lane & 3) * 8;
    const short* gA = A  + (size_t)(m0 + srow) * Dn + scol;
    const short* gB = Bw + (size_t)(n0 + srow) * Dn + scol;
    short* lA = &As[srow * BK + scol];
    short* lB = &Bs[srow * BK + scol];

    f32x4 acc[4][4] = {};

    #pragma unroll 1
    for (int k0 = 0; k0 < Dn; k0 += BK) {
        __syncthreads();
        __builtin_amdgcn_global_load_lds(
            (const __attribute__((address_space(1))) void*)(gA + k0),
            (__attribute__((address_space(3))) void*)lA, 16, 0, 0);
        __builtin_amdgcn_global_load_lds(
            (const __attribute__((address_space(1))) void*)(gA + k0 + (size_t)16 * Dn),
            (__attribute__((address_space(3))) void*)(lA + 16 * BK), 16, 0, 0);
        __builtin_amdgcn_global_load_lds(
            (const __attribute__((address_space(1))) void*)(gB + k0),
            (__attribute__((address_space(3))) void*)lB, 16, 0, 0);
        __builtin_amdgcn_global_load_lds(
            (const __attribute__((address_space(1))) void*)(gB + k0 + (size_t)16 * Dn),
            (__attribute__((address_space(3))) void*)(lB + 16 * BK), 16, 0, 0);
        __syncthreads();

        short8 af[4], bf[4];
        #pragma unroll
        for (int i = 0; i < 4; ++i)
            af[i] = *(const short8*)&As[(wm + i * 16 + r) * BK + quad * 8];
        #pragma unroll
        for (int j = 0; j < 4; ++j)
            bf[j] = *(const short8*)&Bs[(wn + j * 16 + r) * BK + quad * 8];

        #pragma unroll
        for (int i = 0; i < 4; ++i)
            #pragma unroll
            for (int j = 0; j < 4; ++j)
                acc[i][j] = __builtin_amdgcn_mfma_f32_16x16x32_bf16(
                    af[i], bf[j], acc[i][j], 0, 0, 0);
    }

    #pragma unroll
    for (int i = 0; i < 4; ++i) {
        #pragma unroll
        for (int reg = 0; reg < 4; ++reg) {
            const int rowg = m0 + wm + i * 16 + quad * 4 + reg;
            const float bv = bias[rowg];
            #pragma unroll
            for (int j = 0; j < 4; ++j) {
                const int col = n0 + wn + j * 16 + r;
                vT[(size_t)rowg * MT + col] = f2bf(acc[i][j][reg] + bv);
            }
        }
    }
}

// ---------------------------------------------------------------------------
// out GEMM per batch: out[t][g] = sum_s attn[t][s] * vT[g][s].
// 128(t) x 64(g) tile per block -> grid (Gn/64, Bn) = 1024 blocks (4/CU).
// ---------------------------------------------------------------------------
__global__ __launch_bounds__(256) void out_gemm_kernel(
    const short* __restrict__ attn16, const short* __restrict__ vT,
    float* __restrict__ out)
{
    __shared__ __attribute__((aligned(16))) short As[128 * BK];  // 8 KB
    __shared__ __attribute__((aligned(16))) short Bs[64 * BK];   // 4 KB

    const int tid = threadIdx.x;
    const int b  = blockIdx.y;
    const int n0 = blockIdx.x * 64;    // g dim
    const int wave = tid >> 6, lane = tid & 63;
    const int wm = (wave >> 1) * 64, wn = (wave & 1) * 32;
    const int quad = lane >> 4, r = lane & 15;

    const int srowA = wave * 32 + (lane >> 2);   // 0..127 over 2 instrs
    const int srowB = wave * 16 + (lane >> 2);   // 0..63, 1 instr
    const int scol = (lane & 3) * 8;
    const short* gA = attn16 + (size_t)b * Tn * Tn + srowA * Tn + scol;   // t rows
    const short* gB = vT + (size_t)(n0 + srowB) * MT + b * Tn + scol;     // g rows
    short* lA = &As[srowA * BK + scol];
    short* lB = &Bs[srowB * BK + scol];

    f32x4 acc[4][2] = {};

    #pragma unroll 1
    for (int k0 = 0; k0 < Tn; k0 += BK) {
        __syncthreads();
        __builtin_amdgcn_global_load_lds(
            (const __attribute__((address_space(1))) void*)(gA + k0),
            (__attribute__((address_space(3))) void*)lA, 16, 0, 0);
        __builtin_amdgcn_global_load_lds(
            (const __attribute__((address_space(1))) void*)(gA + k0 + 16 * Tn),
            (__attribute__((address_space(3))) void*)(lA + 16 * BK), 16, 0, 0);
        __builtin_amdgcn_global_load_lds(
            (const __attribute__((address_space(1))) void*)(gB + k0),
            (__attribute__((address_space(3))) void*)lB, 16, 0, 0);
        __syncthreads();

        short8 af[4], bf[2];
        #pragma unroll
        for (int i = 0; i < 4; ++i)
            af[i] = *(const short8*)&As[(wm + i * 16 + r) * BK + quad * 8];
        #pragma unroll
        for (int j = 0; j < 2; ++j)
            bf[j] = *(const short8*)&Bs[(wn + j * 16 + r) * BK + quad * 8];

        #pragma unroll
        for (int i = 0; i < 4; ++i)
            #pragma unroll
            for (int j = 0; j < 2; ++j)
                acc[i][j] = __builtin_amdgcn_mfma_f32_16x16x32_bf16(
                    af[i], bf[j], acc[i][j], 0, 0, 0);
    }

    // C/D: row(m=t)=quad*4+reg, col(n=g)=r group. fp32 out [b][t][g].
    #pragma unroll
    for (int j = 0; j < 2; ++j) {
        const int col = n0 + wn + j * 16 + r;
        #pragma unroll
        for (int i = 0; i < 4; ++i) {
            #pragma unroll
            for (int reg = 0; reg < 4; ++reg) {
                const int rowt = wm + i * 16 + quad * 4 + reg;
                out[((size_t)(b * Tn + rowt)) * Gn + col] = acc[i][j][reg];
            }
        }
    }
}

// ---------------------------------------------------------------------------
extern "C" void kernel_launch(void* const* d_in, const int* in_sizes, int n_in,
                              void* d_out, int out_size, void* d_ws, size_t ws_size,
                              hipStream_t stream)
{
    const float* x1 = (const float*)d_in[0];
    const float* x2 = (const float*)d_in[1];
    const float* w1 = (const float*)d_in[2];
    const float* b1 = (const float*)d_in[3];
    const float* w2 = (const float*)d_in[4];
    const float* b2 = (const float*)d_in[5];
    const float* w3 = (const float*)d_in[6];
    const float* b3 = (const float*)d_in[7];
    float* out = (float*)d_out;

    // Workspace: qp,kp fp32 partials; attn16, vT, x1b, w3b bf16; vTf fp32 xK.
    float* qp     = (float*)d_ws;
    float* kp     = qp + (size_t)QKP * MT * Fn;
    short* attn16 = (short*)(kp + (size_t)QKP * MT * Fn);
    short* vT     = attn16 + (size_t)Bn * Tn * Tn;
    short* x1b    = vT + (size_t)Gn * MT;
    short* w3b    = x1b + (size_t)MT * Dn;
    float* vTf    = (float*)(w3b + (size_t)Gn * Dn);

    const size_t base_need =
        (size_t)QKP * MT * Fn * 4 * 2 +         // qp,kp
        (size_t)Bn * Tn * Tn * 2 +              // attn16
        (size_t)Gn * MT * 2 +                   // vT
        (size_t)MT * Dn * 2 +                   // x1b
        (size_t)Gn * Dn * 2;                    // w3b
    const size_t psize = (size_t)Gn * MT * 4;   // 32 MB per partial

    const int ksplit = (ws_size >= base_need + 2 * psize) ? 2 : 0;

    cvt2_kernel<<<4096, 256, 0, stream>>>(x1, w3, x1b, w3b);
    qk_gemm_kernel<<<dim3(256, QKP), 256, 0, stream>>>(x1b, x2, w1, w2, qp, kp);
    attn_kernel<<<dim3(Bn, Tn / 4), 256, 0, stream>>>(qp, kp, b1, b2, attn16);

    if (ksplit) {
        gemm_v_split_kernel<<<dim3(MT / 128, Gn / 128, ksplit), 256, 0, stream>>>(
            w3b, x1b, vTf, Dn / ksplit);
        vt_cvt_kernel<<<2048, 256, 0, stream>>>(vTf, b3, vT, ksplit);
    } else {
        gemm_v_kernel<<<dim3(MT / 128, Gn / 128), 256, 0, stream>>>(w3b, x1b, b3, vT);
    }

    out_gemm_kernel<<<dim3(Gn / 64, Bn), 256, 0, stream>>>(attn16, vT, out);
}

// Round 7
// 521.960 us; speedup vs baseline: 1.0784x; 1.0488x over previous
//
#include <hip/hip_runtime.h>
#include <cstdint>
#include <cstddef>

// Problem constants
#define Bn 16
#define Tn 128
#define Dn 8192    // C*H*W
#define Fn 16      // NUM_FEAT
#define Gn 4096    // NUM_FEAT*H*W
#define MT (Bn*Tn) // 2048 rows

#define QKP 4      // qk split-K parts

typedef __attribute__((ext_vector_type(8))) short short8;
typedef __attribute__((ext_vector_type(4))) float f32x4;

__device__ inline short f2bf(float f) {
    union { float f; uint32_t u; } c; c.f = f;
    uint32_t u = c.u;
    uint32_t r = (u + 0x7FFFu + ((u >> 16) & 1u)) >> 16;
    return (short)(r & 0xFFFFu);
}

__device__ inline short8 cvt8(float4 a, float4 b) {
    short8 v;
    v[0] = f2bf(a.x); v[1] = f2bf(a.y); v[2] = f2bf(a.z); v[3] = f2bf(a.w);
    v[4] = f2bf(b.x); v[5] = f2bf(b.y); v[6] = f2bf(b.z); v[7] = f2bf(b.w);
    return v;
}

// ---------------------------------------------------------------------------
// Fused fp32->bf16 convert for x1 and w3 (one launch, grid-stride).
// ---------------------------------------------------------------------------
#define N8_X1 (MT * Dn / 8)   // 2,097,152
#define N8_W3 ((size_t)Gn * Dn / 8)   // 4,194,304

__global__ __launch_bounds__(256) void cvt2_kernel(
    const float* __restrict__ x1, const float* __restrict__ w3,
    short* __restrict__ x1b, short* __restrict__ w3b)
{
    const size_t total = N8_X1 + N8_W3;
    size_t i = (size_t)blockIdx.x * 256 + threadIdx.x;
    const size_t stride = (size_t)gridDim.x * 256;
    for (; i < total; i += stride) {
        if (i < N8_X1) {
            const float4* s = ((const float4*)x1) + i * 2;
            ((short8*)x1b)[i] = cvt8(s[0], s[1]);
        } else {
            const size_t j = i - N8_X1;
            const float4* s = ((const float4*)w3) + j * 2;
            ((short8*)w3b)[j] = cvt8(s[0], s[1]);
        }
    }
}

// ---------------------------------------------------------------------------
// qk skinny GEMM, split-K x4: partial q/k (NO bias) per K-quarter.
// Grid (256, QKP) x 256 threads. Partials summed (with bias) in attn_kernel.
// ---------------------------------------------------------------------------
__global__ __launch_bounds__(256) void qk_gemm_kernel(
    const short* __restrict__ x1b, const float* __restrict__ x2,
    const float* __restrict__ w1, const float* __restrict__ w2,
    float* __restrict__ qp, float* __restrict__ kp)
{
    __shared__ float red[4][16][16];
    const int tid = threadIdx.x;
    const int tile = blockIdx.x >> 1;
    const int isK  = blockIdx.x & 1;
    const int kq   = blockIdx.y;
    const int m0 = tile * 16;
    const int wave = tid >> 6, lane = tid & 63;
    const int quad = lane >> 4, r = lane & 15;
    const int kbase = kq * (Dn / QKP) + wave * (Dn / QKP / 4);   // kq*2048 + w*512

    f32x4 acc = {};

    if (!isK) {
        const short* ap = x1b + (size_t)(m0 + r) * Dn + kbase + quad * 8;
        const float* bp = w1 + (size_t)r * Dn + kbase + quad * 8;
        #pragma unroll 4
        for (int it = 0; it < 16; ++it) {
            short8 af = *(const short8*)(ap + it * 32);
            const float4* b4 = (const float4*)(bp + it * 32);
            short8 bf = cvt8(b4[0], b4[1]);
            acc = __builtin_amdgcn_mfma_f32_16x16x32_bf16(af, bf, acc, 0, 0, 0);
        }
    } else {
        const float* apf = x2 + (size_t)(m0 + r) * Dn + kbase + quad * 8;
        const float* bp  = w2 + (size_t)r * Dn + kbase + quad * 8;
        #pragma unroll 4
        for (int it = 0; it < 16; ++it) {
            const float4* a4 = (const float4*)(apf + it * 32);
            short8 af = cvt8(a4[0], a4[1]);
            const float4* b4 = (const float4*)(bp + it * 32);
            short8 bf = cvt8(b4[0], b4[1]);
            acc = __builtin_amdgcn_mfma_f32_16x16x32_bf16(af, bf, acc, 0, 0, 0);
        }
    }

    // C/D: col(n=f)=lane&15, row(m)=quad*4+reg
    #pragma unroll
    for (int reg = 0; reg < 4; ++reg)
        red[wave][quad * 4 + reg][r] = acc[reg];
    __syncthreads();

    const int m = tid >> 4, f = tid & 15;
    float s = red[0][m][f] + red[1][m][f] + red[2][m][f] + red[3][m][f];
    float* dst = isK ? kp : qp;
    dst[((size_t)kq * MT + m0 + m) * Fn + f] = s;
}

// ---------------------------------------------------------------------------
// attn: sums qk partials (+bias), scores = q @ k^T per batch; softmax over t
// (axis=1 = per column s). Wave-per-column: grid (Bn, Tn/4) x 256; wave w owns
// s = blockIdx.y*4 + w; lane owns t=lane, t=lane+64. Butterfly shfl reduce.
// ---------------------------------------------------------------------------
__global__ __launch_bounds__(256) void attn_kernel(
    const float* __restrict__ qp, const float* __restrict__ kp,
    const float* __restrict__ b1, const float* __restrict__ b2,
    short* __restrict__ attn16)
{
    __shared__ float qs[Tn * 17];
    const int b = blockIdx.x;
    const int tid = threadIdx.x;
    const int wave = tid >> 6, lane = tid & 63;
    const int s = blockIdx.y * 4 + wave;

    for (int i = tid; i < Tn * Fn; i += 256) {
        float v = b1[i & 15];
        #pragma unroll
        for (int p = 0; p < QKP; ++p)
            v += qp[(size_t)p * MT * Fn + b * Tn * Fn + i];
        qs[(i >> 4) * 17 + (i & 15)] = v;
    }
    __syncthreads();

    float kr[16];
    #pragma unroll
    for (int f = 0; f < 16; ++f) {
        float v = b2[f];
        #pragma unroll
        for (int p = 0; p < QKP; ++p)
            v += kp[((size_t)p * MT + b * Tn + s) * Fn + f];
        kr[f] = v;
    }

    const int t0 = lane, t1 = lane + 64;
    float sc0 = 0.f, sc1 = 0.f;
    #pragma unroll
    for (int f = 0; f < 16; ++f) {
        sc0 += qs[t0 * 17 + f] * kr[f];
        sc1 += qs[t1 * 17 + f] * kr[f];
    }
    float m = fmaxf(sc0, sc1);
    #pragma unroll
    for (int off = 32; off > 0; off >>= 1)
        m = fmaxf(m, __shfl_xor(m, off, 64));
    const float e0 = __expf(sc0 - m), e1 = __expf(sc1 - m);
    float ssum = e0 + e1;
    #pragma unroll
    for (int off = 32; off > 0; off >>= 1)
        ssum += __shfl_xor(ssum, off, 64);
    const float inv = 1.f / ssum;

    short* ap = attn16 + (size_t)b * Tn * Tn;
    ap[t0 * Tn + s] = f2bf(e0 * inv);
    ap[t1 * Tn + s] = f2bf(e1 * inv);
}

// ---------------------------------------------------------------------------
// Big GEMM, split-K (KSPLIT=2), BK=32, now 2-PHASE double-buffered (T3 minimal
// recipe): STAGE tile k+1 is issued BEFORE computing tile k, so the HBM latency
// of the staging loads hides under a full compute phase; ONE barrier per K-step
// (its compiler-emitted vmcnt(0)/lgkmcnt(0) drain provides the sync).
// Race analysis: STAGE(buf^1) writes the buffer whose readers all finished
// before the previous barrier (WAR safe); COMPUTE(buf) follows the barrier
// that drained buf's loads (RAW safe). LDS 2x(8+8)KB = 32 KB -> 4 blocks/CU.
// ---------------------------------------------------------------------------
#define BK 32

__global__ __launch_bounds__(256) void gemm_v_split_kernel(
    const short* __restrict__ A, const short* __restrict__ Bw,
    float* __restrict__ vTf, const int kspan)
{
    __shared__ __attribute__((aligned(16))) short As[2][128 * BK];
    __shared__ __attribute__((aligned(16))) short Bs[2][128 * BK];

    const int tid = threadIdx.x;
    const int m0 = blockIdx.y * 128;        // g dim (4096)
    const int n0 = blockIdx.x * 128;        // bt dim (2048)
    const int z  = blockIdx.z;              // K slice
    const int kbase = z * kspan;
    float* outp = vTf + (size_t)z * Gn * MT;
    const int wave = tid >> 6, lane = tid & 63;
    const int wm = (wave >> 1) * 64, wn = (wave & 1) * 64;
    const int quad = lane >> 4, r = lane & 15;

    const int srow = wave * 32 + (lane >> 2);
    const int scol = (lane & 3) * 8;
    const short* gA = A  + (size_t)(m0 + srow) * Dn + kbase + scol;
    const short* gB = Bw + (size_t)(n0 + srow) * Dn + kbase + scol;

    f32x4 acc[4][4] = {};

#define STAGE(buf, koff)                                                        \
    do {                                                                        \
        __builtin_amdgcn_global_load_lds(                                       \
            (const __attribute__((address_space(1))) void*)(gA + (koff)),       \
            (__attribute__((address_space(3))) void*)&As[buf][srow * BK + scol], 16, 0, 0); \
        __builtin_amdgcn_global_load_lds(                                       \
            (const __attribute__((address_space(1))) void*)(gA + (koff) + (size_t)16 * Dn), \
            (__attribute__((address_space(3))) void*)&As[buf][(srow + 16) * BK + scol], 16, 0, 0); \
        __builtin_amdgcn_global_load_lds(                                       \
            (const __attribute__((address_space(1))) void*)(gB + (koff)),       \
            (__attribute__((address_space(3))) void*)&Bs[buf][srow * BK + scol], 16, 0, 0); \
        __builtin_amdgcn_global_load_lds(                                       \
            (const __attribute__((address_space(1))) void*)(gB + (koff) + (size_t)16 * Dn), \
            (__attribute__((address_space(3))) void*)&Bs[buf][(srow + 16) * BK + scol], 16, 0, 0); \
    } while (0)

#define COMPUTE(buf)                                                            \
    do {                                                                        \
        short8 af[4], bf[4];                                                    \
        _Pragma("unroll")                                                       \
        for (int i = 0; i < 4; ++i)                                             \
            af[i] = *(const short8*)&As[buf][(wm + i * 16 + r) * BK + quad * 8];\
        _Pragma("unroll")                                                       \
        for (int j = 0; j < 4; ++j)                                             \
            bf[j] = *(const short8*)&Bs[buf][(wn + j * 16 + r) * BK + quad * 8];\
        _Pragma("unroll")                                                       \
        for (int i = 0; i < 4; ++i)                                             \
            _Pragma("unroll")                                                   \
            for (int j = 0; j < 4; ++j)                                         \
                acc[i][j] = __builtin_amdgcn_mfma_f32_16x16x32_bf16(            \
                    af[i], bf[j], acc[i][j], 0, 0, 0);                          \
    } while (0)

    STAGE(0, 0);
    __syncthreads();            // drains vmcnt(0): buf0 ready

    int cur = 0;
    #pragma unroll 2
    for (int k0 = BK; k0 < kspan; k0 += BK) {
        STAGE(cur ^ 1, k0);     // issue next tile's loads (hidden under compute)
        COMPUTE(cur);
        __syncthreads();        // drains this step's staged loads; all readers done
        cur ^= 1;
    }
    COMPUTE(cur);               // last tile, no prefetch

#undef STAGE
#undef COMPUTE

    // C/D: col(n=bt)=lane&15 group, row(m=g)=quad*4+reg. Plain fp32 stores.
    #pragma unroll
    for (int i = 0; i < 4; ++i) {
        #pragma unroll
        for (int reg = 0; reg < 4; ++reg) {
            const int rowg = m0 + wm + i * 16 + quad * 4 + reg;
            #pragma unroll
            for (int j = 0; j < 4; ++j) {
                const int col = n0 + wn + j * 16 + r;
                outp[(size_t)rowg * MT + col] = acc[i][j][reg];
            }
        }
    }
}

// ---------------------------------------------------------------------------
// Fallback (ws too small for split-K): original single-pass big GEMM (BK=32),
// writes bf16 vT with bias directly.
// ---------------------------------------------------------------------------
__global__ __launch_bounds__(256) void gemm_v_kernel(
    const short* __restrict__ A, const short* __restrict__ Bw,
    const float* __restrict__ bias, short* __restrict__ vT)
{
    __shared__ __attribute__((aligned(16))) short As[128 * BK];
    __shared__ __attribute__((aligned(16))) short Bs[128 * BK];

    const int tid = threadIdx.x;
    const int m0 = blockIdx.y * 128;   // g dim (4096)
    const int n0 = blockIdx.x * 128;   // bt dim (2048)
    const int wave = tid >> 6, lane = tid & 63;
    const int wm = (wave >> 1) * 64, wn = (wave & 1) * 64;
    const int quad = lane >> 4, r = lane & 15;

    const int srow = wave * 32 + (lane >> 2);
    const int scol = (lane & 3) * 8;
    const short* gA = A  + (size_t)(m0 + srow) * Dn + scol;
    const short* gB = Bw + (size_t)(n0 + srow) * Dn + scol;
    short* lA = &As[srow * BK + scol];
    short* lB = &Bs[srow * BK + scol];

    f32x4 acc[4][4] = {};

    #pragma unroll 1
    for (int k0 = 0; k0 < Dn; k0 += BK) {
        __syncthreads();
        __builtin_amdgcn_global_load_lds(
            (const __attribute__((address_space(1))) void*)(gA + k0),
            (__attribute__((address_space(3))) void*)lA, 16, 0, 0);
        __builtin_amdgcn_global_load_lds(
            (const __attribute__((address_space(1))) void*)(gA + k0 + (size_t)16 * Dn),
            (__attribute__((address_space(3))) void*)(lA + 16 * BK), 16, 0, 0);
        __builtin_amdgcn_global_load_lds(
            (const __attribute__((address_space(1))) void*)(gB + k0),
            (__attribute__((address_space(3))) void*)lB, 16, 0, 0);
        __builtin_amdgcn_global_load_lds(
            (const __attribute__((address_space(1))) void*)(gB + k0 + (size_t)16 * Dn),
            (__attribute__((address_space(3))) void*)(lB + 16 * BK), 16, 0, 0);
        __syncthreads();

        short8 af[4], bf[4];
        #pragma unroll
        for (int i = 0; i < 4; ++i)
            af[i] = *(const short8*)&As[(wm + i * 16 + r) * BK + quad * 8];
        #pragma unroll
        for (int j = 0; j < 4; ++j)
            bf[j] = *(const short8*)&Bs[(wn + j * 16 + r) * BK + quad * 8];

        #pragma unroll
        for (int i = 0; i < 4; ++i)
            #pragma unroll
            for (int j = 0; j < 4; ++j)
                acc[i][j] = __builtin_amdgcn_mfma_f32_16x16x32_bf16(
                    af[i], bf[j], acc[i][j], 0, 0, 0);
    }

    #pragma unroll
    for (int i = 0; i < 4; ++i) {
        #pragma unroll
        for (int reg = 0; reg < 4; ++reg) {
            const int rowg = m0 + wm + i * 16 + quad * 4 + reg;
            const float bv = bias[rowg];
            #pragma unroll
            for (int j = 0; j < 4; ++j) {
                const int col = n0 + wn + j * 16 + r;
                vT[(size_t)rowg * MT + col] = f2bf(acc[i][j][reg] + bv);
            }
        }
    }
}

// ---------------------------------------------------------------------------
// FUSED out GEMM (split path): B-operand is built inline from the TWO fp32
// K-slice partials + bias -> bf16 (bit-identical to the old vt_cvt pass),
// reg-staged + ds_write; A (attn16) keeps global_load_lds. Each vTf element
// is consumed exactly once, so the fusion removes the whole 80 MB vt_cvt pass.
// out[t][g] = sum_s attn[t][s] * v[s][g]. Grid (Gn/64, Bn) = 1024 blocks.
// ---------------------------------------------------------------------------
__global__ __launch_bounds__(256) void out_gemm_fused_kernel(
    const short* __restrict__ attn16, const float* __restrict__ vTf,
    const float* __restrict__ b3, float* __restrict__ out)
{
    __shared__ __attribute__((aligned(16))) short As[128 * BK];  // 8 KB
    __shared__ __attribute__((aligned(16))) short Bs[64 * BK];   // 4 KB

    const int tid = threadIdx.x;
    const int b  = blockIdx.y;
    const int n0 = blockIdx.x * 64;    // g dim
    const int wave = tid >> 6, lane = tid & 63;
    const int wm = (wave >> 1) * 64, wn = (wave & 1) * 32;
    const int quad = lane >> 4, r = lane & 15;

    const int srowA = wave * 32 + (lane >> 2);   // 0..127 over 2 instrs
    const int srowB = wave * 16 + (lane >> 2);   // 0..63, one 8-float slice each
    const int scol = (lane & 3) * 8;
    const short* gA = attn16 + (size_t)b * Tn * Tn + srowA * Tn + scol;      // t rows
    const float* gB0 = vTf + (size_t)(n0 + srowB) * MT + b * Tn + scol;      // part 0
    const float* gB1 = gB0 + (size_t)Gn * MT;                                // part 1
    const float bv = b3[n0 + srowB];
    short* lA = &As[srowA * BK + scol];

    f32x4 acc[4][2] = {};

    #pragma unroll 1
    for (int k0 = 0; k0 < Tn; k0 += BK) {
        __syncthreads();
        __builtin_amdgcn_global_load_lds(
            (const __attribute__((address_space(1))) void*)(gA + k0),
            (__attribute__((address_space(3))) void*)lA, 16, 0, 0);
        __builtin_amdgcn_global_load_lds(
            (const __attribute__((address_space(1))) void*)(gA + k0 + 16 * Tn),
            (__attribute__((address_space(3))) void*)(lA + 16 * BK), 16, 0, 0);
        // B: fp32 partials -> sum + bias -> bf16 -> LDS (replaces vt_cvt).
        {
            const float4* p0 = (const float4*)(gB0 + k0);
            const float4* p1 = (const float4*)(gB1 + k0);
            float4 a0 = p0[0], a1 = p0[1], c0 = p1[0], c1 = p1[1];
            a0.x += c0.x + bv; a0.y += c0.y + bv; a0.z += c0.z + bv; a0.w += c0.w + bv;
            a1.x += c1.x + bv; a1.y += c1.y + bv; a1.z += c1.z + bv; a1.w += c1.w + bv;
            *(short8*)&Bs[srowB * BK + scol] = cvt8(a0, a1);
        }
        __syncthreads();

        short8 af[4], bf[2];
        #pragma unroll
        for (int i = 0; i < 4; ++i)
            af[i] = *(const short8*)&As[(wm + i * 16 + r) * BK + quad * 8];
        #pragma unroll
        for (int j = 0; j < 2; ++j)
            bf[j] = *(const short8*)&Bs[(wn + j * 16 + r) * BK + quad * 8];

        #pragma unroll
        for (int i = 0; i < 4; ++i)
            #pragma unroll
            for (int j = 0; j < 2; ++j)
                acc[i][j] = __builtin_amdgcn_mfma_f32_16x16x32_bf16(
                    af[i], bf[j], acc[i][j], 0, 0, 0);
    }

    // C/D: row(m=t)=quad*4+reg, col(n=g)=r group. fp32 out [b][t][g].
    #pragma unroll
    for (int j = 0; j < 2; ++j) {
        const int col = n0 + wn + j * 16 + r;
        #pragma unroll
        for (int i = 0; i < 4; ++i) {
            #pragma unroll
            for (int reg = 0; reg < 4; ++reg) {
                const int rowt = wm + i * 16 + quad * 4 + reg;
                out[((size_t)(b * Tn + rowt)) * Gn + col] = acc[i][j][reg];
            }
        }
    }
}

// ---------------------------------------------------------------------------
// Fallback out GEMM (reads bf16 vT written by gemm_v_kernel).
// ---------------------------------------------------------------------------
__global__ __launch_bounds__(256) void out_gemm_kernel(
    const short* __restrict__ attn16, const short* __restrict__ vT,
    float* __restrict__ out)
{
    __shared__ __attribute__((aligned(16))) short As[128 * BK];  // 8 KB
    __shared__ __attribute__((aligned(16))) short Bs[64 * BK];   // 4 KB

    const int tid = threadIdx.x;
    const int b  = blockIdx.y;
    const int n0 = blockIdx.x * 64;    // g dim
    const int wave = tid >> 6, lane = tid & 63;
    const int wm = (wave >> 1) * 64, wn = (wave & 1) * 32;
    const int quad = lane >> 4, r = lane & 15;

    const int srowA = wave * 32 + (lane >> 2);
    const int srowB = wave * 16 + (lane >> 2);
    const int scol = (lane & 3) * 8;
    const short* gA = attn16 + (size_t)b * Tn * Tn + srowA * Tn + scol;
    const short* gB = vT + (size_t)(n0 + srowB) * MT + b * Tn + scol;
    short* lA = &As[srowA * BK + scol];
    short* lB = &Bs[srowB * BK + scol];

    f32x4 acc[4][2] = {};

    #pragma unroll 1
    for (int k0 = 0; k0 < Tn; k0 += BK) {
        __syncthreads();
        __builtin_amdgcn_global_load_lds(
            (const __attribute__((address_space(1))) void*)(gA + k0),
            (__attribute__((address_space(3))) void*)lA, 16, 0, 0);
        __builtin_amdgcn_global_load_lds(
            (const __attribute__((address_space(1))) void*)(gA + k0 + 16 * Tn),
            (__attribute__((address_space(3))) void*)(lA + 16 * BK), 16, 0, 0);
        __builtin_amdgcn_global_load_lds(
            (const __attribute__((address_space(1))) void*)(gB + k0),
            (__attribute__((address_space(3))) void*)lB, 16, 0, 0);
        __syncthreads();

        short8 af[4], bf[2];
        #pragma unroll
        for (int i = 0; i < 4; ++i)
            af[i] = *(const short8*)&As[(wm + i * 16 + r) * BK + quad * 8];
        #pragma unroll
        for (int j = 0; j < 2; ++j)
            bf[j] = *(const short8*)&Bs[(wn + j * 16 + r) * BK + quad * 8];

        #pragma unroll
        for (int i = 0; i < 4; ++i)
            #pragma unroll
            for (int j = 0; j < 2; ++j)
                acc[i][j] = __builtin_amdgcn_mfma_f32_16x16x32_bf16(
                    af[i], bf[j], acc[i][j], 0, 0, 0);
    }

    #pragma unroll
    for (int j = 0; j < 2; ++j) {
        const int col = n0 + wn + j * 16 + r;
        #pragma unroll
        for (int i = 0; i < 4; ++i) {
            #pragma unroll
            for (int reg = 0; reg < 4; ++reg) {
                const int rowt = wm + i * 16 + quad * 4 + reg;
                out[((size_t)(b * Tn + rowt)) * Gn + col] = acc[i][j][reg];
            }
        }
    }
}

// ---------------------------------------------------------------------------
extern "C" void kernel_launch(void* const* d_in, const int* in_sizes, int n_in,
                              void* d_out, int out_size, void* d_ws, size_t ws_size,
                              hipStream_t stream)
{
    const float* x1 = (const float*)d_in[0];
    const float* x2 = (const float*)d_in[1];
    const float* w1 = (const float*)d_in[2];
    const float* b1 = (const float*)d_in[3];
    const float* w2 = (const float*)d_in[4];
    const float* b2 = (const float*)d_in[5];
    const float* w3 = (const float*)d_in[6];
    const float* b3 = (const float*)d_in[7];
    float* out = (float*)d_out;

    // Workspace: qp,kp fp32 partials; attn16, vT, x1b, w3b bf16; vTf fp32 x2.
    float* qp     = (float*)d_ws;
    float* kp     = qp + (size_t)QKP * MT * Fn;
    short* attn16 = (short*)(kp + (size_t)QKP * MT * Fn);
    short* vT     = attn16 + (size_t)Bn * Tn * Tn;
    short* x1b    = vT + (size_t)Gn * MT;
    short* w3b    = x1b + (size_t)MT * Dn;
    float* vTf    = (float*)(w3b + (size_t)Gn * Dn);

    const size_t base_need =
        (size_t)QKP * MT * Fn * 4 * 2 +         // qp,kp
        (size_t)Bn * Tn * Tn * 2 +              // attn16
        (size_t)Gn * MT * 2 +                   // vT (fallback only)
        (size_t)MT * Dn * 2 +                   // x1b
        (size_t)Gn * Dn * 2;                    // w3b
    const size_t psize = (size_t)Gn * MT * 4;   // 32 MB per partial

    const int ksplit = (ws_size >= base_need + 2 * psize) ? 2 : 0;

    cvt2_kernel<<<4096, 256, 0, stream>>>(x1, w3, x1b, w3b);
    qk_gemm_kernel<<<dim3(256, QKP), 256, 0, stream>>>(x1b, x2, w1, w2, qp, kp);
    attn_kernel<<<dim3(Bn, Tn / 4), 256, 0, stream>>>(qp, kp, b1, b2, attn16);

    if (ksplit) {
        gemm_v_split_kernel<<<dim3(MT / 128, Gn / 128, 2), 256, 0, stream>>>(
            w3b, x1b, vTf, Dn / 2);
        out_gemm_fused_kernel<<<dim3(Gn / 64, Bn), 256, 0, stream>>>(
            attn16, vTf, b3, out);
    } else {
        gemm_v_kernel<<<dim3(MT / 128, Gn / 128), 256, 0, stream>>>(w3b, x1b, b3, vT);
        out_gemm_kernel<<<dim3(Gn / 64, Bn), 256, 0, stream>>>(attn16, vT, out);
    }
}

// Round 8
// 515.897 us; speedup vs baseline: 1.0911x; 1.0118x over previous
//
#include <hip/hip_runtime.h>
#include <cstdint>
#include <cstddef>

// Problem constants
#define Bn 16
#define Tn 128
#define Dn 8192    // C*H*W
#define Fn 16      // NUM_FEAT
#define Gn 4096    // NUM_FEAT*H*W
#define MT (Bn*Tn) // 2048 rows

#define QKP 4      // qk split-K parts

typedef __attribute__((ext_vector_type(8))) short short8;
typedef __attribute__((ext_vector_type(4))) float f32x4;

__device__ inline short f2bf(float f) {
    union { float f; uint32_t u; } c; c.f = f;
    uint32_t u = c.u;
    uint32_t r = (u + 0x7FFFu + ((u >> 16) & 1u)) >> 16;
    return (short)(r & 0xFFFFu);
}

__device__ inline short8 cvt8(float4 a, float4 b) {
    short8 v;
    v[0] = f2bf(a.x); v[1] = f2bf(a.y); v[2] = f2bf(a.z); v[3] = f2bf(a.w);
    v[4] = f2bf(b.x); v[5] = f2bf(b.y); v[6] = f2bf(b.z); v[7] = f2bf(b.w);
    return v;
}

// ---------------------------------------------------------------------------
// Fused fp32->bf16 convert for x1 and w3 (one launch, grid-stride).
// ---------------------------------------------------------------------------
#define N8_X1 (MT * Dn / 8)   // 2,097,152
#define N8_W3 ((size_t)Gn * Dn / 8)   // 4,194,304

__global__ __launch_bounds__(256) void cvt2_kernel(
    const float* __restrict__ x1, const float* __restrict__ w3,
    short* __restrict__ x1b, short* __restrict__ w3b)
{
    const size_t total = N8_X1 + N8_W3;
    size_t i = (size_t)blockIdx.x * 256 + threadIdx.x;
    const size_t stride = (size_t)gridDim.x * 256;
    for (; i < total; i += stride) {
        if (i < N8_X1) {
            const float4* s = ((const float4*)x1) + i * 2;
            ((short8*)x1b)[i] = cvt8(s[0], s[1]);
        } else {
            const size_t j = i - N8_X1;
            const float4* s = ((const float4*)w3) + j * 2;
            ((short8*)w3b)[j] = cvt8(s[0], s[1]);
        }
    }
}

// ---------------------------------------------------------------------------
// qk skinny GEMM, split-K x4: partial q/k (NO bias) per K-quarter.
// Grid (256, QKP) x 256 threads. Partials summed (with bias) in attn_kernel.
// ---------------------------------------------------------------------------
__global__ __launch_bounds__(256) void qk_gemm_kernel(
    const short* __restrict__ x1b, const float* __restrict__ x2,
    const float* __restrict__ w1, const float* __restrict__ w2,
    float* __restrict__ qp, float* __restrict__ kp)
{
    __shared__ float red[4][16][16];
    const int tid = threadIdx.x;
    const int tile = blockIdx.x >> 1;
    const int isK  = blockIdx.x & 1;
    const int kq   = blockIdx.y;
    const int m0 = tile * 16;
    const int wave = tid >> 6, lane = tid & 63;
    const int quad = lane >> 4, r = lane & 15;
    const int kbase = kq * (Dn / QKP) + wave * (Dn / QKP / 4);   // kq*2048 + w*512

    f32x4 acc = {};

    if (!isK) {
        const short* ap = x1b + (size_t)(m0 + r) * Dn + kbase + quad * 8;
        const float* bp = w1 + (size_t)r * Dn + kbase + quad * 8;
        #pragma unroll 4
        for (int it = 0; it < 16; ++it) {
            short8 af = *(const short8*)(ap + it * 32);
            const float4* b4 = (const float4*)(bp + it * 32);
            short8 bf = cvt8(b4[0], b4[1]);
            acc = __builtin_amdgcn_mfma_f32_16x16x32_bf16(af, bf, acc, 0, 0, 0);
        }
    } else {
        const float* apf = x2 + (size_t)(m0 + r) * Dn + kbase + quad * 8;
        const float* bp  = w2 + (size_t)r * Dn + kbase + quad * 8;
        #pragma unroll 4
        for (int it = 0; it < 16; ++it) {
            const float4* a4 = (const float4*)(apf + it * 32);
            short8 af = cvt8(a4[0], a4[1]);
            const float4* b4 = (const float4*)(bp + it * 32);
            short8 bf = cvt8(b4[0], b4[1]);
            acc = __builtin_amdgcn_mfma_f32_16x16x32_bf16(af, bf, acc, 0, 0, 0);
        }
    }

    // C/D: col(n=f)=lane&15, row(m)=quad*4+reg
    #pragma unroll
    for (int reg = 0; reg < 4; ++reg)
        red[wave][quad * 4 + reg][r] = acc[reg];
    __syncthreads();

    const int m = tid >> 4, f = tid & 15;
    float s = red[0][m][f] + red[1][m][f] + red[2][m][f] + red[3][m][f];
    float* dst = isK ? kp : qp;
    dst[((size_t)kq * MT + m0 + m) * Fn + f] = s;
}

// ---------------------------------------------------------------------------
// attn: sums qk partials (+bias), scores = q @ k^T per batch; softmax over t
// (axis=1 = per column s). Wave-per-column: grid (Bn, Tn/4) x 256; wave w owns
// s = blockIdx.y*4 + w; lane owns t=lane, t=lane+64. Butterfly shfl reduce.
// ---------------------------------------------------------------------------
__global__ __launch_bounds__(256) void attn_kernel(
    const float* __restrict__ qp, const float* __restrict__ kp,
    const float* __restrict__ b1, const float* __restrict__ b2,
    short* __restrict__ attn16)
{
    __shared__ float qs[Tn * 17];
    const int b = blockIdx.x;
    const int tid = threadIdx.x;
    const int wave = tid >> 6, lane = tid & 63;
    const int s = blockIdx.y * 4 + wave;

    for (int i = tid; i < Tn * Fn; i += 256) {
        float v = b1[i & 15];
        #pragma unroll
        for (int p = 0; p < QKP; ++p)
            v += qp[(size_t)p * MT * Fn + b * Tn * Fn + i];
        qs[(i >> 4) * 17 + (i & 15)] = v;
    }
    __syncthreads();

    float kr[16];
    #pragma unroll
    for (int f = 0; f < 16; ++f) {
        float v = b2[f];
        #pragma unroll
        for (int p = 0; p < QKP; ++p)
            v += kp[((size_t)p * MT + b * Tn + s) * Fn + f];
        kr[f] = v;
    }

    const int t0 = lane, t1 = lane + 64;
    float sc0 = 0.f, sc1 = 0.f;
    #pragma unroll
    for (int f = 0; f < 16; ++f) {
        sc0 += qs[t0 * 17 + f] * kr[f];
        sc1 += qs[t1 * 17 + f] * kr[f];
    }
    float m = fmaxf(sc0, sc1);
    #pragma unroll
    for (int off = 32; off > 0; off >>= 1)
        m = fmaxf(m, __shfl_xor(m, off, 64));
    const float e0 = __expf(sc0 - m), e1 = __expf(sc1 - m);
    float ssum = e0 + e1;
    #pragma unroll
    for (int off = 32; off > 0; off >>= 1)
        ssum += __shfl_xor(ssum, off, 64);
    const float inv = 1.f / ssum;

    short* ap = attn16 + (size_t)b * Tn * Tn;
    ap[t0 * Tn + s] = f2bf(e0 * inv);
    ap[t1 * Tn + s] = f2bf(e1 * inv);
}

// ---------------------------------------------------------------------------
// Big GEMM, split-K (KSPLIT=2), BK=32, 2-phase double-buffered (unchanged from
// R7) + NEW: bijective 2D-chunked XCD swizzle (T1). Default dispatch
// round-robins consecutive blocks over 8 XCD L2s, scattering the blocks that
// share A/B panels -> 3.6x L2-miss overfetch (FETCH 350 MB vs 96 MB unique).
// Each XCD now owns an 8n x 8m tile region per K-slice: A panels duplicated
// x2, B panels x4 (balanced optimum ~256 MB L2-miss).
// Mapping (per z-slice, 512 blocks, 512%8==0 -> bijective):
//   flat2 = x + 16y; xcd = flat2&7; idx = flat2>>3;
//   nt = (xcd&1)*8 + (idx&7); mt = (xcd>>1)*8 + (idx>>3).
// ---------------------------------------------------------------------------
#define BK 32

__global__ __launch_bounds__(256) void gemm_v_split_kernel(
    const short* __restrict__ A, const short* __restrict__ Bw,
    float* __restrict__ vTf, const int kspan)
{
    __shared__ __attribute__((aligned(16))) short As[2][128 * BK];
    __shared__ __attribute__((aligned(16))) short Bs[2][128 * BK];

    const int tid = threadIdx.x;
    // XCD-aware block swizzle (see header comment).
    const int flat2 = blockIdx.x + 16 * blockIdx.y;   // 0..511 within z-slice
    const int xcd = flat2 & 7, idx = flat2 >> 3;
    const int nt = ((xcd & 1) << 3) | (idx & 7);      // 0..15
    const int mt = ((xcd >> 1) << 3) | (idx >> 3);    // 0..31
    const int m0 = mt * 128;                // g dim (4096)
    const int n0 = nt * 128;                // bt dim (2048)
    const int z  = blockIdx.z;              // K slice
    const int kbase = z * kspan;
    float* outp = vTf + (size_t)z * Gn * MT;
    const int wave = tid >> 6, lane = tid & 63;
    const int wm = (wave >> 1) * 64, wn = (wave & 1) * 64;
    const int quad = lane >> 4, r = lane & 15;

    const int srow = wave * 32 + (lane >> 2);
    const int scol = (lane & 3) * 8;
    const short* gA = A  + (size_t)(m0 + srow) * Dn + kbase + scol;
    const short* gB = Bw + (size_t)(n0 + srow) * Dn + kbase + scol;

    f32x4 acc[4][4] = {};

#define STAGE(buf, koff)                                                        \
    do {                                                                        \
        __builtin_amdgcn_global_load_lds(                                       \
            (const __attribute__((address_space(1))) void*)(gA + (koff)),       \
            (__attribute__((address_space(3))) void*)&As[buf][srow * BK + scol], 16, 0, 0); \
        __builtin_amdgcn_global_load_lds(                                       \
            (const __attribute__((address_space(1))) void*)(gA + (koff) + (size_t)16 * Dn), \
            (__attribute__((address_space(3))) void*)&As[buf][(srow + 16) * BK + scol], 16, 0, 0); \
        __builtin_amdgcn_global_load_lds(                                       \
            (const __attribute__((address_space(1))) void*)(gB + (koff)),       \
            (__attribute__((address_space(3))) void*)&Bs[buf][srow * BK + scol], 16, 0, 0); \
        __builtin_amdgcn_global_load_lds(                                       \
            (const __attribute__((address_space(1))) void*)(gB + (koff) + (size_t)16 * Dn), \
            (__attribute__((address_space(3))) void*)&Bs[buf][(srow + 16) * BK + scol], 16, 0, 0); \
    } while (0)

#define COMPUTE(buf)                                                            \
    do {                                                                        \
        short8 af[4], bf[4];                                                    \
        _Pragma("unroll")                                                       \
        for (int i = 0; i < 4; ++i)                                             \
            af[i] = *(const short8*)&As[buf][(wm + i * 16 + r) * BK + quad * 8];\
        _Pragma("unroll")                                                       \
        for (int j = 0; j < 4; ++j)                                             \
            bf[j] = *(const short8*)&Bs[buf][(wn + j * 16 + r) * BK + quad * 8];\
        _Pragma("unroll")                                                       \
        for (int i = 0; i < 4; ++i)                                             \
            _Pragma("unroll")                                                   \
            for (int j = 0; j < 4; ++j)                                         \
                acc[i][j] = __builtin_amdgcn_mfma_f32_16x16x32_bf16(            \
                    af[i], bf[j], acc[i][j], 0, 0, 0);                          \
    } while (0)

    STAGE(0, 0);
    __syncthreads();            // drains vmcnt(0): buf0 ready

    int cur = 0;
    #pragma unroll 2
    for (int k0 = BK; k0 < kspan; k0 += BK) {
        STAGE(cur ^ 1, k0);     // issue next tile's loads (hidden under compute)
        COMPUTE(cur);
        __syncthreads();        // drains this step's staged loads; all readers done
        cur ^= 1;
    }
    COMPUTE(cur);               // last tile, no prefetch

#undef STAGE
#undef COMPUTE

    // C/D: col(n=bt)=lane&15 group, row(m=g)=quad*4+reg. Plain fp32 stores.
    #pragma unroll
    for (int i = 0; i < 4; ++i) {
        #pragma unroll
        for (int reg = 0; reg < 4; ++reg) {
            const int rowg = m0 + wm + i * 16 + quad * 4 + reg;
            #pragma unroll
            for (int j = 0; j < 4; ++j) {
                const int col = n0 + wn + j * 16 + r;
                outp[(size_t)rowg * MT + col] = acc[i][j][reg];
            }
        }
    }
}

// ---------------------------------------------------------------------------
// Fallback (ws too small for split-K): original single-pass big GEMM (BK=32),
// writes bf16 vT with bias directly.
// ---------------------------------------------------------------------------
__global__ __launch_bounds__(256) void gemm_v_kernel(
    const short* __restrict__ A, const short* __restrict__ Bw,
    const float* __restrict__ bias, short* __restrict__ vT)
{
    __shared__ __attribute__((aligned(16))) short As[128 * BK];
    __shared__ __attribute__((aligned(16))) short Bs[128 * BK];

    const int tid = threadIdx.x;
    const int m0 = blockIdx.y * 128;   // g dim (4096)
    const int n0 = blockIdx.x * 128;   // bt dim (2048)
    const int wave = tid >> 6, lane = tid & 63;
    const int wm = (wave >> 1) * 64, wn = (wave & 1) * 64;
    const int quad = lane >> 4, r = lane & 15;

    const int srow = wave * 32 + (lane >> 2);
    const int scol = (lane & 3) * 8;
    const short* gA = A  + (size_t)(m0 + srow) * Dn + scol;
    const short* gB = Bw + (size_t)(n0 + srow) * Dn + scol;
    short* lA = &As[srow * BK + scol];
    short* lB = &Bs[srow * BK + scol];

    f32x4 acc[4][4] = {};

    #pragma unroll 1
    for (int k0 = 0; k0 < Dn; k0 += BK) {
        __syncthreads();
        __builtin_amdgcn_global_load_lds(
            (const __attribute__((address_space(1))) void*)(gA + k0),
            (__attribute__((address_space(3))) void*)lA, 16, 0, 0);
        __builtin_amdgcn_global_load_lds(
            (const __attribute__((address_space(1))) void*)(gA + k0 + (size_t)16 * Dn),
            (__attribute__((address_space(3))) void*)(lA + 16 * BK), 16, 0, 0);
        __builtin_amdgcn_global_load_lds(
            (const __attribute__((address_space(1))) void*)(gB + k0),
            (__attribute__((address_space(3))) void*)lB, 16, 0, 0);
        __builtin_amdgcn_global_load_lds(
            (const __attribute__((address_space(1))) void*)(gB + k0 + (size_t)16 * Dn),
            (__attribute__((address_space(3))) void*)(lB + 16 * BK), 16, 0, 0);
        __syncthreads();

        short8 af[4], bf[4];
        #pragma unroll
        for (int i = 0; i < 4; ++i)
            af[i] = *(const short8*)&As[(wm + i * 16 + r) * BK + quad * 8];
        #pragma unroll
        for (int j = 0; j < 4; ++j)
            bf[j] = *(const short8*)&Bs[(wn + j * 16 + r) * BK + quad * 8];

        #pragma unroll
        for (int i = 0; i < 4; ++i)
            #pragma unroll
            for (int j = 0; j < 4; ++j)
                acc[i][j] = __builtin_amdgcn_mfma_f32_16x16x32_bf16(
                    af[i], bf[j], acc[i][j], 0, 0, 0);
    }

    #pragma unroll
    for (int i = 0; i < 4; ++i) {
        #pragma unroll
        for (int reg = 0; reg < 4; ++reg) {
            const int rowg = m0 + wm + i * 16 + quad * 4 + reg;
            const float bv = bias[rowg];
            #pragma unroll
            for (int j = 0; j < 4; ++j) {
                const int col = n0 + wn + j * 16 + r;
                vT[(size_t)rowg * MT + col] = f2bf(acc[i][j][reg] + bv);
            }
        }
    }
}

// ---------------------------------------------------------------------------
// FUSED out GEMM (split path): B-operand built inline from the TWO fp32
// K-slice partials + bias -> bf16 (replaces the vt_cvt pass).
// out[t][g] = sum_s attn[t][s] * v[s][g]. Grid (Gn/64, Bn) = 1024 blocks.
// ---------------------------------------------------------------------------
__global__ __launch_bounds__(256) void out_gemm_fused_kernel(
    const short* __restrict__ attn16, const float* __restrict__ vTf,
    const float* __restrict__ b3, float* __restrict__ out)
{
    __shared__ __attribute__((aligned(16))) short As[128 * BK];  // 8 KB
    __shared__ __attribute__((aligned(16))) short Bs[64 * BK];   // 4 KB

    const int tid = threadIdx.x;
    const int b  = blockIdx.y;
    const int n0 = blockIdx.x * 64;    // g dim
    const int wave = tid >> 6, lane = tid & 63;
    const int wm = (wave >> 1) * 64, wn = (wave & 1) * 32;
    const int quad = lane >> 4, r = lane & 15;

    const int srowA = wave * 32 + (lane >> 2);   // 0..127 over 2 instrs
    const int srowB = wave * 16 + (lane >> 2);   // 0..63, one 8-float slice each
    const int scol = (lane & 3) * 8;
    const short* gA = attn16 + (size_t)b * Tn * Tn + srowA * Tn + scol;      // t rows
    const float* gB0 = vTf + (size_t)(n0 + srowB) * MT + b * Tn + scol;      // part 0
    const float* gB1 = gB0 + (size_t)Gn * MT;                                // part 1
    const float bv = b3[n0 + srowB];
    short* lA = &As[srowA * BK + scol];

    f32x4 acc[4][2] = {};

    #pragma unroll 1
    for (int k0 = 0; k0 < Tn; k0 += BK) {
        __syncthreads();
        __builtin_amdgcn_global_load_lds(
            (const __attribute__((address_space(1))) void*)(gA + k0),
            (__attribute__((address_space(3))) void*)lA, 16, 0, 0);
        __builtin_amdgcn_global_load_lds(
            (const __attribute__((address_space(1))) void*)(gA + k0 + 16 * Tn),
            (__attribute__((address_space(3))) void*)(lA + 16 * BK), 16, 0, 0);
        // B: fp32 partials -> sum + bias -> bf16 -> LDS (replaces vt_cvt).
        {
            const float4* p0 = (const float4*)(gB0 + k0);
            const float4* p1 = (const float4*)(gB1 + k0);
            float4 a0 = p0[0], a1 = p0[1], c0 = p1[0], c1 = p1[1];
            a0.x += c0.x + bv; a0.y += c0.y + bv; a0.z += c0.z + bv; a0.w += c0.w + bv;
            a1.x += c1.x + bv; a1.y += c1.y + bv; a1.z += c1.z + bv; a1.w += c1.w + bv;
            *(short8*)&Bs[srowB * BK + scol] = cvt8(a0, a1);
        }
        __syncthreads();

        short8 af[4], bf[2];
        #pragma unroll
        for (int i = 0; i < 4; ++i)
            af[i] = *(const short8*)&As[(wm + i * 16 + r) * BK + quad * 8];
        #pragma unroll
        for (int j = 0; j < 2; ++j)
            bf[j] = *(const short8*)&Bs[(wn + j * 16 + r) * BK + quad * 8];

        #pragma unroll
        for (int i = 0; i < 4; ++i)
            #pragma unroll
            for (int j = 0; j < 2; ++j)
                acc[i][j] = __builtin_amdgcn_mfma_f32_16x16x32_bf16(
                    af[i], bf[j], acc[i][j], 0, 0, 0);
    }

    // C/D: row(m=t)=quad*4+reg, col(n=g)=r group. fp32 out [b][t][g].
    #pragma unroll
    for (int j = 0; j < 2; ++j) {
        const int col = n0 + wn + j * 16 + r;
        #pragma unroll
        for (int i = 0; i < 4; ++i) {
            #pragma unroll
            for (int reg = 0; reg < 4; ++reg) {
                const int rowt = wm + i * 16 + quad * 4 + reg;
                out[((size_t)(b * Tn + rowt)) * Gn + col] = acc[i][j][reg];
            }
        }
    }
}

// ---------------------------------------------------------------------------
// Fallback out GEMM (reads bf16 vT written by gemm_v_kernel).
// ---------------------------------------------------------------------------
__global__ __launch_bounds__(256) void out_gemm_kernel(
    const short* __restrict__ attn16, const short* __restrict__ vT,
    float* __restrict__ out)
{
    __shared__ __attribute__((aligned(16))) short As[128 * BK];  // 8 KB
    __shared__ __attribute__((aligned(16))) short Bs[64 * BK];   // 4 KB

    const int tid = threadIdx.x;
    const int b  = blockIdx.y;
    const int n0 = blockIdx.x * 64;    // g dim
    const int wave = tid >> 6, lane = tid & 63;
    const int wm = (wave >> 1) * 64, wn = (wave & 1) * 32;
    const int quad = lane >> 4, r = lane & 15;

    const int srowA = wave * 32 + (lane >> 2);
    const int srowB = wave * 16 + (lane >> 2);
    const int scol = (lane & 3) * 8;
    const short* gA = attn16 + (size_t)b * Tn * Tn + srowA * Tn + scol;
    const short* gB = vT + (size_t)(n0 + srowB) * MT + b * Tn + scol;
    short* lA = &As[srowA * BK + scol];
    short* lB = &Bs[srowB * BK + scol];

    f32x4 acc[4][2] = {};

    #pragma unroll 1
    for (int k0 = 0; k0 < Tn; k0 += BK) {
        __syncthreads();
        __builtin_amdgcn_global_load_lds(
            (const __attribute__((address_space(1))) void*)(gA + k0),
            (__attribute__((address_space(3))) void*)lA, 16, 0, 0);
        __builtin_amdgcn_global_load_lds(
            (const __attribute__((address_space(1))) void*)(gA + k0 + 16 * Tn),
            (__attribute__((address_space(3))) void*)(lA + 16 * BK), 16, 0, 0);
        __builtin_amdgcn_global_load_lds(
            (const __attribute__((address_space(1))) void*)(gB + k0),
            (__attribute__((address_space(3))) void*)lB, 16, 0, 0);
        __syncthreads();

        short8 af[4], bf[2];
        #pragma unroll
        for (int i = 0; i < 4; ++i)
            af[i] = *(const short8*)&As[(wm + i * 16 + r) * BK + quad * 8];
        #pragma unroll
        for (int j = 0; j < 2; ++j)
            bf[j] = *(const short8*)&Bs[(wn + j * 16 + r) * BK + quad * 8];

        #pragma unroll
        for (int i = 0; i < 4; ++i)
            #pragma unroll
            for (int j = 0; j < 2; ++j)
                acc[i][j] = __builtin_amdgcn_mfma_f32_16x16x32_bf16(
                    af[i], bf[j], acc[i][j], 0, 0, 0);
    }

    #pragma unroll
    for (int j = 0; j < 2; ++j) {
        const int col = n0 + wn + j * 16 + r;
        #pragma unroll
        for (int i = 0; i < 4; ++i) {
            #pragma unroll
            for (int reg = 0; reg < 4; ++reg) {
                const int rowt = wm + i * 16 + quad * 4 + reg;
                out[((size_t)(b * Tn + rowt)) * Gn + col] = acc[i][j][reg];
            }
        }
    }
}

// ---------------------------------------------------------------------------
extern "C" void kernel_launch(void* const* d_in, const int* in_sizes, int n_in,
                              void* d_out, int out_size, void* d_ws, size_t ws_size,
                              hipStream_t stream)
{
    const float* x1 = (const float*)d_in[0];
    const float* x2 = (const float*)d_in[1];
    const float* w1 = (const float*)d_in[2];
    const float* b1 = (const float*)d_in[3];
    const float* w2 = (const float*)d_in[4];
    const float* b2 = (const float*)d_in[5];
    const float* w3 = (const float*)d_in[6];
    const float* b3 = (const float*)d_in[7];
    float* out = (float*)d_out;

    // Workspace: qp,kp fp32 partials; attn16, vT, x1b, w3b bf16; vTf fp32 x2.
    float* qp     = (float*)d_ws;
    float* kp     = qp + (size_t)QKP * MT * Fn;
    short* attn16 = (short*)(kp + (size_t)QKP * MT * Fn);
    short* vT     = attn16 + (size_t)Bn * Tn * Tn;
    short* x1b    = vT + (size_t)Gn * MT;
    short* w3b    = x1b + (size_t)MT * Dn;
    float* vTf    = (float*)(w3b + (size_t)Gn * Dn);

    const size_t base_need =
        (size_t)QKP * MT * Fn * 4 * 2 +         // qp,kp
        (size_t)Bn * Tn * Tn * 2 +              // attn16
        (size_t)Gn * MT * 2 +                   // vT (fallback only)
        (size_t)MT * Dn * 2 +                   // x1b
        (size_t)Gn * Dn * 2;                    // w3b
    const size_t psize = (size_t)Gn * MT * 4;   // 32 MB per partial

    const int ksplit = (ws_size >= base_need + 2 * psize) ? 2 : 0;

    cvt2_kernel<<<4096, 256, 0, stream>>>(x1, w3, x1b, w3b);
    qk_gemm_kernel<<<dim3(256, QKP), 256, 0, stream>>>(x1b, x2, w1, w2, qp, kp);
    attn_kernel<<<dim3(Bn, Tn / 4), 256, 0, stream>>>(qp, kp, b1, b2, attn16);

    if (ksplit) {
        gemm_v_split_kernel<<<dim3(MT / 128, Gn / 128, 2), 256, 0, stream>>>(
            w3b, x1b, vTf, Dn / 2);
        out_gemm_fused_kernel<<<dim3(Gn / 64, Bn), 256, 0, stream>>>(
            attn16, vTf, b3, out);
    } else {
        gemm_v_kernel<<<dim3(MT / 128, Gn / 128), 256, 0, stream>>>(w3b, x1b, b3, vT);
        out_gemm_kernel<<<dim3(Gn / 64, Bn), 256, 0, stream>>>(attn16, vT, out);
    }
}

// Round 9
// 507.578 us; speedup vs baseline: 1.1089x; 1.0164x over previous
//
#include <hip/hip_runtime.h>
#include <cstdint>
#include <cstddef>

// Problem constants
#define Bn 16
#define Tn 128
#define Dn 8192    // C*H*W
#define Fn 16      // NUM_FEAT
#define Gn 4096    // NUM_FEAT*H*W
#define MT (Bn*Tn) // 2048 rows

#define QKP 4      // qk split-K parts

typedef __attribute__((ext_vector_type(8))) short short8;
typedef __attribute__((ext_vector_type(4))) float f32x4;

__device__ inline short f2bf(float f) {
    union { float f; uint32_t u; } c; c.f = f;
    uint32_t u = c.u;
    uint32_t r = (u + 0x7FFFu + ((u >> 16) & 1u)) >> 16;
    return (short)(r & 0xFFFFu);
}

__device__ inline short8 cvt8(float4 a, float4 b) {
    short8 v;
    v[0] = f2bf(a.x); v[1] = f2bf(a.y); v[2] = f2bf(a.z); v[3] = f2bf(a.w);
    v[4] = f2bf(b.x); v[5] = f2bf(b.y); v[6] = f2bf(b.z); v[7] = f2bf(b.w);
    return v;
}

// ---------------------------------------------------------------------------
// Fused fp32->bf16 convert for x1 and w3 (one launch, grid-stride).
// ---------------------------------------------------------------------------
#define N8_X1 (MT * Dn / 8)   // 2,097,152
#define N8_W3 ((size_t)Gn * Dn / 8)   // 4,194,304

__global__ __launch_bounds__(256) void cvt2_kernel(
    const float* __restrict__ x1, const float* __restrict__ w3,
    short* __restrict__ x1b, short* __restrict__ w3b)
{
    const size_t total = N8_X1 + N8_W3;
    size_t i = (size_t)blockIdx.x * 256 + threadIdx.x;
    const size_t stride = (size_t)gridDim.x * 256;
    for (; i < total; i += stride) {
        if (i < N8_X1) {
            const float4* s = ((const float4*)x1) + i * 2;
            ((short8*)x1b)[i] = cvt8(s[0], s[1]);
        } else {
            const size_t j = i - N8_X1;
            const float4* s = ((const float4*)w3) + j * 2;
            ((short8*)w3b)[j] = cvt8(s[0], s[1]);
        }
    }
}

// ---------------------------------------------------------------------------
// qk skinny GEMM, split-K x4: partial q/k (NO bias) per K-quarter.
// Grid (256, QKP) x 256 threads. Partials summed (with bias) in attn_kernel.
// ---------------------------------------------------------------------------
__global__ __launch_bounds__(256) void qk_gemm_kernel(
    const short* __restrict__ x1b, const float* __restrict__ x2,
    const float* __restrict__ w1, const float* __restrict__ w2,
    float* __restrict__ qp, float* __restrict__ kp)
{
    __shared__ float red[4][16][16];
    const int tid = threadIdx.x;
    const int tile = blockIdx.x >> 1;
    const int isK  = blockIdx.x & 1;
    const int kq   = blockIdx.y;
    const int m0 = tile * 16;
    const int wave = tid >> 6, lane = tid & 63;
    const int quad = lane >> 4, r = lane & 15;
    const int kbase = kq * (Dn / QKP) + wave * (Dn / QKP / 4);   // kq*2048 + w*512

    f32x4 acc = {};

    if (!isK) {
        const short* ap = x1b + (size_t)(m0 + r) * Dn + kbase + quad * 8;
        const float* bp = w1 + (size_t)r * Dn + kbase + quad * 8;
        #pragma unroll 4
        for (int it = 0; it < 16; ++it) {
            short8 af = *(const short8*)(ap + it * 32);
            const float4* b4 = (const float4*)(bp + it * 32);
            short8 bf = cvt8(b4[0], b4[1]);
            acc = __builtin_amdgcn_mfma_f32_16x16x32_bf16(af, bf, acc, 0, 0, 0);
        }
    } else {
        const float* apf = x2 + (size_t)(m0 + r) * Dn + kbase + quad * 8;
        const float* bp  = w2 + (size_t)r * Dn + kbase + quad * 8;
        #pragma unroll 4
        for (int it = 0; it < 16; ++it) {
            const float4* a4 = (const float4*)(apf + it * 32);
            short8 af = cvt8(a4[0], a4[1]);
            const float4* b4 = (const float4*)(bp + it * 32);
            short8 bf = cvt8(b4[0], b4[1]);
            acc = __builtin_amdgcn_mfma_f32_16x16x32_bf16(af, bf, acc, 0, 0, 0);
        }
    }

    // C/D: col(n=f)=lane&15, row(m)=quad*4+reg
    #pragma unroll
    for (int reg = 0; reg < 4; ++reg)
        red[wave][quad * 4 + reg][r] = acc[reg];
    __syncthreads();

    const int m = tid >> 4, f = tid & 15;
    float s = red[0][m][f] + red[1][m][f] + red[2][m][f] + red[3][m][f];
    float* dst = isK ? kp : qp;
    dst[((size_t)kq * MT + m0 + m) * Fn + f] = s;
}

// ---------------------------------------------------------------------------
// attn: sums qk partials (+bias), scores = q @ k^T per batch; softmax over t
// (axis=1 = per column s). Wave-per-column: grid (Bn, Tn/4) x 256; wave w owns
// s = blockIdx.y*4 + w; lane owns t=lane, t=lane+64. Butterfly shfl reduce.
// ---------------------------------------------------------------------------
__global__ __launch_bounds__(256) void attn_kernel(
    const float* __restrict__ qp, const float* __restrict__ kp,
    const float* __restrict__ b1, const float* __restrict__ b2,
    short* __restrict__ attn16)
{
    __shared__ float qs[Tn * 17];
    const int b = blockIdx.x;
    const int tid = threadIdx.x;
    const int wave = tid >> 6, lane = tid & 63;
    const int s = blockIdx.y * 4 + wave;

    for (int i = tid; i < Tn * Fn; i += 256) {
        float v = b1[i & 15];
        #pragma unroll
        for (int p = 0; p < QKP; ++p)
            v += qp[(size_t)p * MT * Fn + b * Tn * Fn + i];
        qs[(i >> 4) * 17 + (i & 15)] = v;
    }
    __syncthreads();

    float kr[16];
    #pragma unroll
    for (int f = 0; f < 16; ++f) {
        float v = b2[f];
        #pragma unroll
        for (int p = 0; p < QKP; ++p)
            v += kp[((size_t)p * MT + b * Tn + s) * Fn + f];
        kr[f] = v;
    }

    const int t0 = lane, t1 = lane + 64;
    float sc0 = 0.f, sc1 = 0.f;
    #pragma unroll
    for (int f = 0; f < 16; ++f) {
        sc0 += qs[t0 * 17 + f] * kr[f];
        sc1 += qs[t1 * 17 + f] * kr[f];
    }
    float m = fmaxf(sc0, sc1);
    #pragma unroll
    for (int off = 32; off > 0; off >>= 1)
        m = fmaxf(m, __shfl_xor(m, off, 64));
    const float e0 = __expf(sc0 - m), e1 = __expf(sc1 - m);
    float ssum = e0 + e1;
    #pragma unroll
    for (int off = 32; off > 0; off >>= 1)
        ssum += __shfl_xor(ssum, off, 64);
    const float inv = 1.f / ssum;

    short* ap = attn16 + (size_t)b * Tn * Tn;
    ap[t0 * Tn + s] = f2bf(e0 * inv);
    ap[t1 * Tn + s] = f2bf(e1 * inv);
}

// ---------------------------------------------------------------------------
// Big GEMM, split-K (KSPLIT=2), BK=32, XCD-swizzled (R8), now with a
// COUNTED-VMCNT pipeline (T4, AITER pattern — never drain vmcnt to 0 in the
// main loop). Steady state per K-step:
//   COMPUTE(cur) -> s_barrier (all waves done READING cur)
//   STAGE(cur, t+2) (4 gload_lds/wave, re-filling cur 2 tiles ahead)
//   s_waitcnt vmcnt(4) (oldest tile's 4 loads landed; newest 4 stay in flight
//   ACROSS the barrier) -> s_barrier (cross-wave visibility: every wave
//   waited vmcnt(4) pre-barrier => whole next tile resident).
// sched_barrier(0) after each raw s_barrier pins compile-time order (raw
// s_barrier is not an LDS fence); COMPUTE interior left scheduler-free.
// ---------------------------------------------------------------------------
#define BK 32

__global__ __launch_bounds__(256) void gemm_v_split_kernel(
    const short* __restrict__ A, const short* __restrict__ Bw,
    float* __restrict__ vTf, const int kspan)
{
    __shared__ __attribute__((aligned(16))) short As[2][128 * BK];
    __shared__ __attribute__((aligned(16))) short Bs[2][128 * BK];

    const int tid = threadIdx.x;
    // XCD-aware block swizzle (bijective; 512 blocks/slice, 512%8==0).
    const int flat2 = blockIdx.x + 16 * blockIdx.y;   // 0..511 within z-slice
    const int xcd = flat2 & 7, idx = flat2 >> 3;
    const int nt = ((xcd & 1) << 3) | (idx & 7);      // 0..15
    const int mt = ((xcd >> 1) << 3) | (idx >> 3);    // 0..31
    const int m0 = mt * 128;                // g dim (4096)
    const int n0 = nt * 128;                // bt dim (2048)
    const int z  = blockIdx.z;              // K slice
    const int kbase = z * kspan;
    float* outp = vTf + (size_t)z * Gn * MT;
    const int wave = tid >> 6, lane = tid & 63;
    const int wm = (wave >> 1) * 64, wn = (wave & 1) * 64;
    const int quad = lane >> 4, r = lane & 15;

    const int srow = wave * 32 + (lane >> 2);
    const int scol = (lane & 3) * 8;
    const short* gA = A  + (size_t)(m0 + srow) * Dn + kbase + scol;
    const short* gB = Bw + (size_t)(n0 + srow) * Dn + kbase + scol;

    f32x4 acc[4][4] = {};

#define STAGE(buf, koff)                                                        \
    do {                                                                        \
        __builtin_amdgcn_global_load_lds(                                       \
            (const __attribute__((address_space(1))) void*)(gA + (koff)),       \
            (__attribute__((address_space(3))) void*)&As[buf][srow * BK + scol], 16, 0, 0); \
        __builtin_amdgcn_global_load_lds(                                       \
            (const __attribute__((address_space(1))) void*)(gA + (koff) + (size_t)16 * Dn), \
            (__attribute__((address_space(3))) void*)&As[buf][(srow + 16) * BK + scol], 16, 0, 0); \
        __builtin_amdgcn_global_load_lds(                                       \
            (const __attribute__((address_space(1))) void*)(gB + (koff)),       \
            (__attribute__((address_space(3))) void*)&Bs[buf][srow * BK + scol], 16, 0, 0); \
        __builtin_amdgcn_global_load_lds(                                       \
            (const __attribute__((address_space(1))) void*)(gB + (koff) + (size_t)16 * Dn), \
            (__attribute__((address_space(3))) void*)&Bs[buf][(srow + 16) * BK + scol], 16, 0, 0); \
    } while (0)

#define COMPUTE(buf)                                                            \
    do {                                                                        \
        short8 af[4], bf[4];                                                    \
        _Pragma("unroll")                                                       \
        for (int i = 0; i < 4; ++i)                                             \
            af[i] = *(const short8*)&As[buf][(wm + i * 16 + r) * BK + quad * 8];\
        _Pragma("unroll")                                                       \
        for (int j = 0; j < 4; ++j)                                             \
            bf[j] = *(const short8*)&Bs[buf][(wn + j * 16 + r) * BK + quad * 8];\
        _Pragma("unroll")                                                       \
        for (int i = 0; i < 4; ++i)                                             \
            _Pragma("unroll")                                                   \
            for (int j = 0; j < 4; ++j)                                         \
                acc[i][j] = __builtin_amdgcn_mfma_f32_16x16x32_bf16(            \
                    af[i], bf[j], acc[i][j], 0, 0, 0);                          \
    } while (0)

#define BAR_SCHED()                                                             \
    do {                                                                        \
        __builtin_amdgcn_s_barrier();                                           \
        __builtin_amdgcn_sched_barrier(0);                                      \
    } while (0)

    // Prologue: stage tiles 0 and 1 (8 loads/wave outstanding).
    STAGE(0, 0);
    STAGE(1, BK);
    asm volatile("s_waitcnt vmcnt(4)" ::: "memory");  // tile0's 4 landed
    BAR_SCHED();                                      // tile0 visible block-wide

    int cur = 0;
    // Invariant at loop top: buf[cur]=tile t (resident), buf[cur^1]=tile t+1
    // (4 loads/wave in flight). 126 iterations (tiles 2..127 staged).
    #pragma unroll 2
    for (int k0 = 2 * BK; k0 < kspan; k0 += BK) {
        COMPUTE(cur);                 // read tile t
        BAR_SCHED();                  // all waves done reading buf[cur]
        STAGE(cur, k0);               // refill buf[cur] with tile t+2
        asm volatile("s_waitcnt vmcnt(4)" ::: "memory");  // tile t+1 landed
        BAR_SCHED();                  // tile t+1 visible block-wide
        cur ^= 1;
    }
    // buf[cur]=tile 126 resident, buf[cur^1]=tile 127 in flight.
    COMPUTE(cur);
    asm volatile("s_waitcnt vmcnt(0)" ::: "memory");
    BAR_SCHED();
    COMPUTE(cur ^ 1);

#undef STAGE
#undef COMPUTE
#undef BAR_SCHED

    // C/D: col(n=bt)=lane&15 group, row(m=g)=quad*4+reg. Plain fp32 stores.
    #pragma unroll
    for (int i = 0; i < 4; ++i) {
        #pragma unroll
        for (int reg = 0; reg < 4; ++reg) {
            const int rowg = m0 + wm + i * 16 + quad * 4 + reg;
            #pragma unroll
            for (int j = 0; j < 4; ++j) {
                const int col = n0 + wn + j * 16 + r;
                outp[(size_t)rowg * MT + col] = acc[i][j][reg];
            }
        }
    }
}

// ---------------------------------------------------------------------------
// Fallback (ws too small for split-K): original single-pass big GEMM (BK=32),
// writes bf16 vT with bias directly.
// ---------------------------------------------------------------------------
__global__ __launch_bounds__(256) void gemm_v_kernel(
    const short* __restrict__ A, const short* __restrict__ Bw,
    const float* __restrict__ bias, short* __restrict__ vT)
{
    __shared__ __attribute__((aligned(16))) short As[128 * BK];
    __shared__ __attribute__((aligned(16))) short Bs[128 * BK];

    const int tid = threadIdx.x;
    const int m0 = blockIdx.y * 128;   // g dim (4096)
    const int n0 = blockIdx.x * 128;   // bt dim (2048)
    const int wave = tid >> 6, lane = tid & 63;
    const int wm = (wave >> 1) * 64, wn = (wave & 1) * 64;
    const int quad = lane >> 4, r = lane & 15;

    const int srow = wave * 32 + (lane >> 2);
    const int scol = (lane & 3) * 8;
    const short* gA = A  + (size_t)(m0 + srow) * Dn + scol;
    const short* gB = Bw + (size_t)(n0 + srow) * Dn + scol;
    short* lA = &As[srow * BK + scol];
    short* lB = &Bs[srow * BK + scol];

    f32x4 acc[4][4] = {};

    #pragma unroll 1
    for (int k0 = 0; k0 < Dn; k0 += BK) {
        __syncthreads();
        __builtin_amdgcn_global_load_lds(
            (const __attribute__((address_space(1))) void*)(gA + k0),
            (__attribute__((address_space(3))) void*)lA, 16, 0, 0);
        __builtin_amdgcn_global_load_lds(
            (const __attribute__((address_space(1))) void*)(gA + k0 + (size_t)16 * Dn),
            (__attribute__((address_space(3))) void*)(lA + 16 * BK), 16, 0, 0);
        __builtin_amdgcn_global_load_lds(
            (const __attribute__((address_space(1))) void*)(gB + k0),
            (__attribute__((address_space(3))) void*)lB, 16, 0, 0);
        __builtin_amdgcn_global_load_lds(
            (const __attribute__((address_space(1))) void*)(gB + k0 + (size_t)16 * Dn),
            (__attribute__((address_space(3))) void*)(lB + 16 * BK), 16, 0, 0);
        __syncthreads();

        short8 af[4], bf[4];
        #pragma unroll
        for (int i = 0; i < 4; ++i)
            af[i] = *(const short8*)&As[(wm + i * 16 + r) * BK + quad * 8];
        #pragma unroll
        for (int j = 0; j < 4; ++j)
            bf[j] = *(const short8*)&Bs[(wn + j * 16 + r) * BK + quad * 8];

        #pragma unroll
        for (int i = 0; i < 4; ++i)
            #pragma unroll
            for (int j = 0; j < 4; ++j)
                acc[i][j] = __builtin_amdgcn_mfma_f32_16x16x32_bf16(
                    af[i], bf[j], acc[i][j], 0, 0, 0);
    }

    #pragma unroll
    for (int i = 0; i < 4; ++i) {
        #pragma unroll
        for (int reg = 0; reg < 4; ++reg) {
            const int rowg = m0 + wm + i * 16 + quad * 4 + reg;
            const float bv = bias[rowg];
            #pragma unroll
            for (int j = 0; j < 4; ++j) {
                const int col = n0 + wn + j * 16 + r;
                vT[(size_t)rowg * MT + col] = f2bf(acc[i][j][reg] + bv);
            }
        }
    }
}

// ---------------------------------------------------------------------------
// FUSED out GEMM (split path): B-operand built inline from the TWO fp32
// K-slice partials + bias -> bf16 (replaces the vt_cvt pass).
// out[t][g] = sum_s attn[t][s] * v[s][g]. Grid (Gn/64, Bn) = 1024 blocks.
// ---------------------------------------------------------------------------
__global__ __launch_bounds__(256) void out_gemm_fused_kernel(
    const short* __restrict__ attn16, const float* __restrict__ vTf,
    const float* __restrict__ b3, float* __restrict__ out)
{
    __shared__ __attribute__((aligned(16))) short As[128 * BK];  // 8 KB
    __shared__ __attribute__((aligned(16))) short Bs[64 * BK];   // 4 KB

    const int tid = threadIdx.x;
    const int b  = blockIdx.y;
    const int n0 = blockIdx.x * 64;    // g dim
    const int wave = tid >> 6, lane = tid & 63;
    const int wm = (wave >> 1) * 64, wn = (wave & 1) * 32;
    const int quad = lane >> 4, r = lane & 15;

    const int srowA = wave * 32 + (lane >> 2);   // 0..127 over 2 instrs
    const int srowB = wave * 16 + (lane >> 2);   // 0..63, one 8-float slice each
    const int scol = (lane & 3) * 8;
    const short* gA = attn16 + (size_t)b * Tn * Tn + srowA * Tn + scol;      // t rows
    const float* gB0 = vTf + (size_t)(n0 + srowB) * MT + b * Tn + scol;      // part 0
    const float* gB1 = gB0 + (size_t)Gn * MT;                                // part 1
    const float bv = b3[n0 + srowB];
    short* lA = &As[srowA * BK + scol];

    f32x4 acc[4][2] = {};

    #pragma unroll 1
    for (int k0 = 0; k0 < Tn; k0 += BK) {
        __syncthreads();
        __builtin_amdgcn_global_load_lds(
            (const __attribute__((address_space(1))) void*)(gA + k0),
            (__attribute__((address_space(3))) void*)lA, 16, 0, 0);
        __builtin_amdgcn_global_load_lds(
            (const __attribute__((address_space(1))) void*)(gA + k0 + 16 * Tn),
            (__attribute__((address_space(3))) void*)(lA + 16 * BK), 16, 0, 0);
        // B: fp32 partials -> sum + bias -> bf16 -> LDS (replaces vt_cvt).
        {
            const float4* p0 = (const float4*)(gB0 + k0);
            const float4* p1 = (const float4*)(gB1 + k0);
            float4 a0 = p0[0], a1 = p0[1], c0 = p1[0], c1 = p1[1];
            a0.x += c0.x + bv; a0.y += c0.y + bv; a0.z += c0.z + bv; a0.w += c0.w + bv;
            a1.x += c1.x + bv; a1.y += c1.y + bv; a1.z += c1.z + bv; a1.w += c1.w + bv;
            *(short8*)&Bs[srowB * BK + scol] = cvt8(a0, a1);
        }
        __syncthreads();

        short8 af[4], bf[2];
        #pragma unroll
        for (int i = 0; i < 4; ++i)
            af[i] = *(const short8*)&As[(wm + i * 16 + r) * BK + quad * 8];
        #pragma unroll
        for (int j = 0; j < 2; ++j)
            bf[j] = *(const short8*)&Bs[(wn + j * 16 + r) * BK + quad * 8];

        #pragma unroll
        for (int i = 0; i < 4; ++i)
            #pragma unroll
            for (int j = 0; j < 2; ++j)
                acc[i][j] = __builtin_amdgcn_mfma_f32_16x16x32_bf16(
                    af[i], bf[j], acc[i][j], 0, 0, 0);
    }

    // C/D: row(m=t)=quad*4+reg, col(n=g)=r group. fp32 out [b][t][g].
    #pragma unroll
    for (int j = 0; j < 2; ++j) {
        const int col = n0 + wn + j * 16 + r;
        #pragma unroll
        for (int i = 0; i < 4; ++i) {
            #pragma unroll
            for (int reg = 0; reg < 4; ++reg) {
                const int rowt = wm + i * 16 + quad * 4 + reg;
                out[((size_t)(b * Tn + rowt)) * Gn + col] = acc[i][j][reg];
            }
        }
    }
}

// ---------------------------------------------------------------------------
// Fallback out GEMM (reads bf16 vT written by gemm_v_kernel).
// ---------------------------------------------------------------------------
__global__ __launch_bounds__(256) void out_gemm_kernel(
    const short* __restrict__ attn16, const short* __restrict__ vT,
    float* __restrict__ out)
{
    __shared__ __attribute__((aligned(16))) short As[128 * BK];  // 8 KB
    __shared__ __attribute__((aligned(16))) short Bs[64 * BK];   // 4 KB

    const int tid = threadIdx.x;
    const int b  = blockIdx.y;
    const int n0 = blockIdx.x * 64;    // g dim
    const int wave = tid >> 6, lane = tid & 63;
    const int wm = (wave >> 1) * 64, wn = (wave & 1) * 32;
    const int quad = lane >> 4, r = lane & 15;

    const int srowA = wave * 32 + (lane >> 2);
    const int srowB = wave * 16 + (lane >> 2);
    const int scol = (lane & 3) * 8;
    const short* gA = attn16 + (size_t)b * Tn * Tn + srowA * Tn + scol;
    const short* gB = vT + (size_t)(n0 + srowB) * MT + b * Tn + scol;
    short* lA = &As[srowA * BK + scol];
    short* lB = &Bs[srowB * BK + scol];

    f32x4 acc[4][2] = {};

    #pragma unroll 1
    for (int k0 = 0; k0 < Tn; k0 += BK) {
        __syncthreads();
        __builtin_amdgcn_global_load_lds(
            (const __attribute__((address_space(1))) void*)(gA + k0),
            (__attribute__((address_space(3))) void*)lA, 16, 0, 0);
        __builtin_amdgcn_global_load_lds(
            (const __attribute__((address_space(1))) void*)(gA + k0 + 16 * Tn),
            (__attribute__((address_space(3))) void*)(lA + 16 * BK), 16, 0, 0);
        __builtin_amdgcn_global_load_lds(
            (const __attribute__((address_space(1))) void*)(gB + k0),
            (__attribute__((address_space(3))) void*)lB, 16, 0, 0);
        __syncthreads();

        short8 af[4], bf[2];
        #pragma unroll
        for (int i = 0; i < 4; ++i)
            af[i] = *(const short8*)&As[(wm + i * 16 + r) * BK + quad * 8];
        #pragma unroll
        for (int j = 0; j < 2; ++j)
            bf[j] = *(const short8*)&Bs[(wn + j * 16 + r) * BK + quad * 8];

        #pragma unroll
        for (int i = 0; i < 4; ++i)
            #pragma unroll
            for (int j = 0; j < 2; ++j)
                acc[i][j] = __builtin_amdgcn_mfma_f32_16x16x32_bf16(
                    af[i], bf[j], acc[i][j], 0, 0, 0);
    }

    #pragma unroll
    for (int j = 0; j < 2; ++j) {
        const int col = n0 + wn + j * 16 + r;
        #pragma unroll
        for (int i = 0; i < 4; ++i) {
            #pragma unroll
            for (int reg = 0; reg < 4; ++reg) {
                const int rowt = wm + i * 16 + quad * 4 + reg;
                out[((size_t)(b * Tn + rowt)) * Gn + col] = acc[i][j][reg];
            }
        }
    }
}

// ---------------------------------------------------------------------------
extern "C" void kernel_launch(void* const* d_in, const int* in_sizes, int n_in,
                              void* d_out, int out_size, void* d_ws, size_t ws_size,
                              hipStream_t stream)
{
    const float* x1 = (const float*)d_in[0];
    const float* x2 = (const float*)d_in[1];
    const float* w1 = (const float*)d_in[2];
    const float* b1 = (const float*)d_in[3];
    const float* w2 = (const float*)d_in[4];
    const float* b2 = (const float*)d_in[5];
    const float* w3 = (const float*)d_in[6];
    const float* b3 = (const float*)d_in[7];
    float* out = (float*)d_out;

    // Workspace: qp,kp fp32 partials; attn16, vT, x1b, w3b bf16; vTf fp32 x2.
    float* qp     = (float*)d_ws;
    float* kp     = qp + (size_t)QKP * MT * Fn;
    short* attn16 = (short*)(kp + (size_t)QKP * MT * Fn);
    short* vT     = attn16 + (size_t)Bn * Tn * Tn;
    short* x1b    = vT + (size_t)Gn * MT;
    short* w3b    = x1b + (size_t)MT * Dn;
    float* vTf    = (float*)(w3b + (size_t)Gn * Dn);

    const size_t base_need =
        (size_t)QKP * MT * Fn * 4 * 2 +         // qp,kp
        (size_t)Bn * Tn * Tn * 2 +              // attn16
        (size_t)Gn * MT * 2 +                   // vT (fallback only)
        (size_t)MT * Dn * 2 +                   // x1b
        (size_t)Gn * Dn * 2;                    // w3b
    const size_t psize = (size_t)Gn * MT * 4;   // 32 MB per partial

    const int ksplit = (ws_size >= base_need + 2 * psize) ? 2 : 0;

    cvt2_kernel<<<4096, 256, 0, stream>>>(x1, w3, x1b, w3b);
    qk_gemm_kernel<<<dim3(256, QKP), 256, 0, stream>>>(x1b, x2, w1, w2, qp, kp);
    attn_kernel<<<dim3(Bn, Tn / 4), 256, 0, stream>>>(qp, kp, b1, b2, attn16);

    if (ksplit) {
        gemm_v_split_kernel<<<dim3(MT / 128, Gn / 128, 2), 256, 0, stream>>>(
            w3b, x1b, vTf, Dn / 2);
        out_gemm_fused_kernel<<<dim3(Gn / 64, Bn), 256, 0, stream>>>(
            attn16, vTf, b3, out);
    } else {
        gemm_v_kernel<<<dim3(MT / 128, Gn / 128), 256, 0, stream>>>(w3b, x1b, b3, vT);
        out_gemm_kernel<<<dim3(Gn / 64, Bn), 256, 0, stream>>>(attn16, vT, out);
    }
}